// Round 7
// baseline (464.146 us; speedup 1.0000x reference)
//
#include <hip/hip_runtime.h>
#include <hip/hip_bf16.h>

// Problem: RandomProjectionQuantizer  B=4 N=4096 D=1024 E=512 K=4096
// M = B*N = 16384 rows.
// proj = X @ P (fp32), scores = 2*invr_m*invc_k*(cb_k . proj_m) - cnsq_k,
// nearest = argmax_k score (ties -> min k).
// Round 18: 3-waves/SIMD argmax via 64x32 wave tile.
// Model (r12-r17 data): per CU chunk-round, L1 return ~2048 cyc vs MFMA
// ~1958 cyc - perfectly overlapped would be ~55-60us; we run 173 because
// 2 waves/SIMD can't cover VMEM queue tails (8 waves/CU bursting 16 loads
// each -> ~2k cyc drain ~ the whole prefetch lead).  i8 halved bytes AND
// pipe work -> stall fraction unchanged (latency/queueing signature).
// Lever: occupancy.  Wave tile 64x64 -> 64x32: acc 128 -> 64 regs, total
// ~150 -> 3 waves/SIMD (launch_bounds(256,3)).  K-loop keeps r14's exact
// proven skeleton (bset dbl at chunk start, ah reload after P2, al after
// P3) with ni=2.  Block 128x64, grid 8192, 4mb x 8nbc swizzle.  Epilogue/
// combine2/fix use r16's 64-group versions (correctness-proven).

#define M_ROWS 16384
#define D_DIM  1024
#define E_DIM  512
#define K_CB   4096
#define EPS_N  1e-12f
#define TAU_FIX 4e-4f
#define NEG_INF (-3.4e38f)
#define S_A_NUM 12.0f   // fixed A-scale: proj elem std ~1.155, 12.0 ~ 10.4 sigma

typedef short bf16x8 __attribute__((ext_vector_type(8)));
typedef _Float16 f16x8 __attribute__((ext_vector_type(8)));
typedef short s16x4 __attribute__((ext_vector_type(4)));
typedef float f32x4  __attribute__((ext_vector_type(4)));
typedef int   i32x4  __attribute__((ext_vector_type(4)));

// ---------------------------------------------------------------- helpers
__device__ __forceinline__ unsigned short f32_to_bf16_rtne(float x) {
  unsigned u = __float_as_uint(x);
  unsigned r = u + 0x7FFFu + ((u >> 16) & 1u);
  return (unsigned short)(r >> 16);
}
__device__ __forceinline__ float bf16_bits_to_f32(unsigned short h) {
  return __uint_as_float(((unsigned)h) << 16);
}
__device__ __forceinline__ void split_f16(float x, short& hs, short& ls) {
  _Float16 h = (_Float16)x;
  float hf = (float)h;
  _Float16 l = (_Float16)(x - hf);
  hs = __builtin_bit_cast(short, h);
  ls = __builtin_bit_cast(short, l);
}
__device__ __forceinline__ void g2l16(const void* g, void* l) {
  __builtin_amdgcn_global_load_lds(
      (const __attribute__((address_space(1))) unsigned*)g,
      (__attribute__((address_space(3))) unsigned*)l, 16, 0, 0);
}
__device__ __forceinline__ i32x4 mfma_i8(i32x4 a, i32x4 b, i32x4 c) {
  return __builtin_amdgcn_mfma_i32_16x16x64_i8(a, b, c, 0, 0, 0);
}
// quantize x (already scaled to q-units, |q|<=16256) into h,l int8
__device__ __forceinline__ void split_i8(float qv, signed char& h,
                                         signed char& l) {
  float hf = rintf(qv * (1.0f / 128.0f));
  float lf = qv - 128.0f * hf;
  h = (signed char)(int)hf;
  l = (signed char)(int)lf;
}

// ---------------------------------------------------------------- row norms
__global__ __launch_bounds__(256) void row_norm_kernel(
    const float* __restrict__ src, float* __restrict__ inv_out,
    float* __restrict__ sq_out, int* __restrict__ zero_me) {
  if (zero_me && blockIdx.x == 0 && threadIdx.x == 0) *zero_me = 0;
  int row  = blockIdx.x * 4 + (threadIdx.x >> 6);
  int lane = threadIdx.x & 63;
  const float4* p = (const float4*)(src + (size_t)row * E_DIM);
  float4 v0 = p[lane];
  float4 v1 = p[lane + 64];
  float s = v0.x * v0.x + v0.y * v0.y + v0.z * v0.z + v0.w * v0.w +
            v1.x * v1.x + v1.y * v1.y + v1.z * v1.z + v1.w * v1.w;
#pragma unroll
  for (int m = 32; m; m >>= 1) s += __shfl_xor(s, m, 64);
  float d = fmaxf(sqrtf(s), EPS_N);
  if (sq_out) {
    float q0 = v0.x / d, q1 = v0.y / d, q2 = v0.z / d, q3 = v0.w / d;
    float q4 = v1.x / d, q5 = v1.y / d, q6 = v1.z / d, q7 = v1.w / d;
    float q = q0 * q0 + q1 * q1 + q2 * q2 + q3 * q3 +
              q4 * q4 + q5 * q5 + q6 * q6 + q7 * q7;
#pragma unroll
    for (int m = 32; m; m >>= 1) q += __shfl_xor(q, m, 64);
    if (lane == 0) sq_out[row] = q;
  }
  if (lane == 0) inv_out[row] = 1.0f / d;
}

// ---------------------------------------------------------------- cb norm+split
// Per codebook row: invc, cnsq, per-row i8 scale sB, and i8 h/l fragments in
// mfma_i32_16x16x64_i8 B-layout: byte idx =
// ((nb*8 + kc8)*512 + q*128 + row128)*16 + j16, kc8=k>>6, q=(k&63)>>4, j16=k&15.
__global__ __launch_bounds__(256) void cbnorm_split_kernel(
    const float* __restrict__ cb, float* __restrict__ invc,
    float* __restrict__ cnsq, float* __restrict__ sB,
    signed char* __restrict__ Bhq, signed char* __restrict__ Blq,
    int* __restrict__ zero_me) {
  if (zero_me && blockIdx.x == 0 && threadIdx.x == 0) *zero_me = 0;
  int r    = blockIdx.x * 4 + (threadIdx.x >> 6);
  int lane = threadIdx.x & 63;
  const float* src = cb + (size_t)r * E_DIM + lane * 8;
  float4 v0 = *(const float4*)src;
  float4 v1 = *(const float4*)(src + 4);
  float v[8] = {v0.x, v0.y, v0.z, v0.w, v1.x, v1.y, v1.z, v1.w};
  float s = 0.f;
#pragma unroll
  for (int j = 0; j < 8; ++j) s = fmaf(v[j], v[j], s);
#pragma unroll
  for (int m = 32; m; m >>= 1) s += __shfl_xor(s, m, 64);
  float d = fmaxf(sqrtf(s), EPS_N);
  float q = 0.f;
#pragma unroll
  for (int j = 0; j < 8; ++j) { float t = v[j] / d; q = fmaf(t, t, q); }
#pragma unroll
  for (int m = 32; m; m >>= 1) q += __shfl_xor(q, m, 64);
  float am = 0.f;
#pragma unroll
  for (int j = 0; j < 8; ++j) am = fmaxf(am, fabsf(v[j]));
#pragma unroll
  for (int m = 32; m; m >>= 1) am = fmaxf(am, __shfl_xor(am, m, 64));
  float inv_sb = (am > 0.f) ? (16256.0f / am) : 0.0f;
  if (lane == 0) {
    cnsq[r] = q;
    invc[r] = 1.0f / d;
    sB[r] = (am > 0.f) ? (am / 16256.0f) : 0.0f;
  }
  union { signed char c8[8]; uint2 u; } Hq, Lq;
#pragma unroll
  for (int j = 0; j < 8; ++j) {
    float qv = rintf(v[j] * inv_sb);  // |qv| <= 16256 by construction
    split_i8(qv, Hq.c8[j], Lq.c8[j]);
  }
  int nb = r >> 7, row = r & 127;
  int kc8 = lane >> 3, qq = (lane & 7) >> 1, jh = lane & 1;
  size_t idx = (((size_t)(nb * 8 + kc8) * 512) + qq * 128 + row) * 16 + jh * 8;
  *(uint2*)(Bhq + idx) = Hq.u;
  *(uint2*)(Blq + idx) = Lq.u;
}

// ---------------------------------------------------------------- P split
__global__ __launch_bounds__(256) void psplit_kernel(
    const float* __restrict__ P, short* __restrict__ Ph,
    short* __restrict__ Pl) {
  int tid = threadIdx.x;
#pragma unroll
  for (int i = 0; i < 4; ++i) {
    int g = blockIdx.x * 1024 + i * 256 + tid;  // 0..65535
    int k8 = g >> 9, col = g & 511;
    int nb = col >> 7, c = col & 127;
    int kc = k8 >> 2, q = k8 & 3;
    union { short s8[8]; float4 f; } H, L;
#pragma unroll
    for (int j = 0; j < 8; ++j) {
      float v = P[(size_t)(k8 * 8 + j) * 512 + col] * 4096.0f;
      split_f16(v, H.s8[j], L.s8[j]);
    }
    size_t dst = (((size_t)(nb * 32 + kc) * 4 + q) * 128 + c) * 8;
    *(float4*)(Ph + dst) = H.f;
    *(float4*)(Pl + dst) = L.f;
  }
}

// ---------------------------------------------------------------- GEMM1 (MFMA)
// proj = X @ P via fp16-split MFMA (hh+hl+lh), scale 4096^2 backed out.
// Epilogue writes proj fp32 + i8 h/l A-fragments (fixed scale 12/16256) in
// mfma_i32_16x16x64_i8 A-layout.
__global__ __launch_bounds__(256, 2) void gemm1_mfma_kernel(
    const float* __restrict__ X, const short* __restrict__ Ph,
    const short* __restrict__ Pl, float* __restrict__ proj,
    signed char* __restrict__ Ahq, signed char* __restrict__ Alq) {
  __shared__ short lds_ah[4096];
  __shared__ short lds_al[4096];
  __shared__ short lds_bh[4096];
  __shared__ short lds_bl[4096];
  int tid = threadIdx.x;
  int wid = tid >> 6, lane = tid & 63;
  int nb = blockIdx.x, mb = blockIdx.y;
  int m0 = mb * 128, n0 = nb * 128;
  int wm = wid >> 1, wn = wid & 1;
  int q4 = lane >> 4, c0 = lane & 15;

  f32x4 zero = {0.f, 0.f, 0.f, 0.f};
  f32x4 acc[4][4];
#pragma unroll
  for (int i = 0; i < 4; ++i)
#pragma unroll
    for (int j = 0; j < 4; ++j) acc[i][j] = zero;

  for (int kc = 0; kc < 32; ++kc) {
    const char* gb = (const char*)Ph + ((size_t)(nb * 32 + kc)) * 8192;
    const char* gl = (const char*)Pl + ((size_t)(nb * 32 + kc)) * 8192;
#pragma unroll
    for (int p = 0; p < 4; ++p) {
      int s = wid * 4 + p;
      int t = s >> 3;
      int off = (s & 7) * 1024;
      const char* src = (t == 0 ? gb : gl) + off + lane * 16;
      char* dst = (char*)(t == 0 ? lds_bh : lds_bl) + off;
      g2l16(src, dst);
    }
#pragma unroll
    for (int i = 0; i < 4; ++i) {
      int e = i * 1024 + tid * 4;
      int row = e >> 5, k4 = e & 31;
      int q = k4 >> 3, j0 = k4 & 7;
      float4 xv = *(const float4*)(X + (size_t)(m0 + row) * D_DIM + kc * 32 + k4);
      float v[4] = {xv.x * 4096.f, xv.y * 4096.f, xv.z * 4096.f, xv.w * 4096.f};
      s16x4 H, L;
#pragma unroll
      for (int j = 0; j < 4; ++j) {
        short hs, ls;
        split_f16(v[j], hs, ls);
        H[j] = hs; L[j] = ls;
      }
      int o = (q * 128 + row) * 8 + j0;
      *(s16x4*)&lds_ah[o] = H;
      *(s16x4*)&lds_al[o] = L;
    }
    __syncthreads();

    f16x8 bh[4], bl[4];
#pragma unroll
    for (int ni = 0; ni < 4; ++ni) {
      int boff = (q4 * 128 + wn * 64 + ni * 16 + c0) * 8;
      bh[ni] = *(const f16x8*)&lds_bh[boff];
      bl[ni] = *(const f16x8*)&lds_bl[boff];
    }
#pragma unroll
    for (int mi = 0; mi < 4; ++mi) {
      int aoff = (q4 * 128 + wm * 64 + mi * 16 + c0) * 8;
      f16x8 ah = *(const f16x8*)&lds_ah[aoff];
      f16x8 al = *(const f16x8*)&lds_al[aoff];
#pragma unroll
      for (int ni = 0; ni < 4; ++ni) {
        acc[mi][ni] = __builtin_amdgcn_mfma_f32_16x16x32_f16(
            ah, bh[ni], acc[mi][ni], 0, 0, 0);
        acc[mi][ni] = __builtin_amdgcn_mfma_f32_16x16x32_f16(
            ah, bl[ni], acc[mi][ni], 0, 0, 0);
        acc[mi][ni] = __builtin_amdgcn_mfma_f32_16x16x32_f16(
            al, bh[ni], acc[mi][ni], 0, 0, 0);
      }
    }
    __syncthreads();
  }

  const float inv_s = 1.0f / 16777216.0f;
  const float QA = 16256.0f / S_A_NUM;
#pragma unroll
  for (int ni = 0; ni < 4; ++ni) {
    int gcol = n0 + wn * 64 + ni * 16 + c0;
    int kc8 = gcol >> 6, qe = (gcol & 63) >> 4, je = gcol & 15;
    size_t ibase = (((size_t)(mb * 8 + kc8) * 512) + qe * 128) * 16 + je;
#pragma unroll
    for (int mi = 0; mi < 4; ++mi) {
#pragma unroll
      for (int r = 0; r < 4; ++r) {
        int rl = wm * 64 + mi * 16 + q4 * 4 + r;
        float val = acc[mi][ni][r] * inv_s;
        proj[(size_t)(m0 + rl) * E_DIM + gcol] = val;
        float qv = rintf(fminf(fmaxf(val * QA, -16256.f), 16256.f));
        signed char hq, lq;
        split_i8(qv, hq, lq);
        size_t idx = ibase + (size_t)rl * 16;
        Ahq[idx] = hq;
        Alq[idx] = lq;
      }
    }
  }
}

// ---------------------------------------------------------------- MFMA argmax
// INT8 reg-direct barrier-free K-loop, r14 skeleton, 64x32 wave tile for
// 3 waves/SIMD.  Grid 8192, swizzled 4mb x 8nbc tiles.  Block 128 rows x
// 64 cols, 4 waves 2x2 (wave 64x32: accH[4][2]+accM[4][2] = 64 regs).
// Per K-chunk (K=64): P1 accH += ah.bh (8 MFMA); P2 accM += ah.bl (8);
// reload ah(next); P3 accM += al.bh (8); reload al(next).  B (bh,bl)
// double-buffered at chunk start.  ~150 VGPR -> 3 waves/SIMD.
__device__ __forceinline__ void ld_a4(i32x4 (&d)[4], const char* p, int kc) {
#pragma unroll
  for (int i = 0; i < 4; ++i)
    d[i] = *(const i32x4*)(p + kc * 8192 + i * 256);
}
__device__ __forceinline__ void ld_b2(i32x4 (&d)[2], const char* p, int kc) {
#pragma unroll
  for (int i = 0; i < 2; ++i)
    d[i] = *(const i32x4*)(p + kc * 8192 + i * 256);
}
__device__ __forceinline__ void mm8(i32x4 (&acc)[4][2], const i32x4 (&a)[4],
                                    const i32x4 (&b)[2]) {
#pragma unroll
  for (int mi = 0; mi < 4; ++mi)
#pragma unroll
    for (int ni = 0; ni < 2; ++ni)
      acc[mi][ni] = mfma_i8(a[mi], b[ni], acc[mi][ni]);
}

__global__ __launch_bounds__(256, 3) void mfma_argmax_kernel(
    const signed char* __restrict__ Ahq, const signed char* __restrict__ Alq,
    const signed char* __restrict__ Bhq, const signed char* __restrict__ Blq,
    const float* __restrict__ invr, const float* __restrict__ invc,
    const float* __restrict__ cnsq, const float* __restrict__ sB,
    float* __restrict__ candb, float* __restrict__ cands2,
    int* __restrict__ candi) {
  __shared__ float msb[2][128];
  __shared__ float mss[2][128];
  __shared__ int   msi[2][128];
  int tid = threadIdx.x;
  int wid = tid >> 6, lane = tid & 63;
  // swizzle: 32-block tiles of 4 mb x 8 nbc for per-XCD L2 locality
  int lin = blockIdx.x;
  int tile = lin >> 5, wi = lin & 31;
  int tnb = tile & 7, tmb = tile >> 3;   // tnb 0..7, tmb 0..31
  int nbc = tnb * 8 + (wi & 7);          // 0..63 (64-col groups)
  int mb  = tmb * 4 + (wi >> 3);         // 0..127

  int wm = wid >> 1, wn = wid & 1;
  int q = lane >> 4, c0 = lane & 15;
  int nb = nbc >> 1, half = nbc & 1;

  // per-lane fragment base pointers (byte units; 65536 B per 128-panel)
  const char* pAh = (const char*)Ahq + (size_t)mb * 65536 +
                    (q * 128 + wm * 64 + c0) * 16;
  const char* pAl = (const char*)Alq + (size_t)mb * 65536 +
                    (q * 128 + wm * 64 + c0) * 16;
  const char* pBh = (const char*)Bhq + (size_t)nb * 65536 +
                    (q * 128 + half * 64 + wn * 32 + c0) * 16;
  const char* pBl = (const char*)Blq + (size_t)nb * 65536 +
                    (q * 128 + half * 64 + wn * 32 + c0) * 16;

  i32x4 zero = {0, 0, 0, 0};
  i32x4 accH[4][2], accM[4][2];
#pragma unroll
  for (int i = 0; i < 4; ++i)
#pragma unroll
    for (int j = 0; j < 2; ++j) { accH[i][j] = zero; accM[i][j] = zero; }

  i32x4 ah[4], al[4], bh0[2], bl0[2], bh1[2], bl1[2];
  ld_b2(bh0, pBh, 0);
  ld_b2(bl0, pBl, 0);
  ld_a4(ah, pAh, 0);
  ld_a4(al, pAl, 0);
  for (int t = 0; t < 6; t += 2) {
    // even chunk t: ah/al/bh0/bl0
    ld_b2(bh1, pBh, t + 1);
    ld_b2(bl1, pBl, t + 1);
    mm8(accH, ah, bh0);                  // P1: hh
    mm8(accM, ah, bl0);                  // P2: hl (ah dead)
    ld_a4(ah, pAh, t + 1);
    mm8(accM, al, bh0);                  // P3: lh (al, bh0, bl0 dead)
    ld_a4(al, pAl, t + 1);
    // odd chunk t+1: ah/al/bh1/bl1
    ld_b2(bh0, pBh, t + 2);
    ld_b2(bl0, pBl, t + 2);
    mm8(accH, ah, bh1);
    mm8(accM, ah, bl1);
    ld_a4(ah, pAh, t + 2);
    mm8(accM, al, bh1);
    ld_a4(al, pAl, t + 2);
  }
  // chunks 6 and 7 (no prefetch past the end)
  ld_b2(bh1, pBh, 7);
  ld_b2(bl1, pBl, 7);
  mm8(accH, ah, bh0);
  mm8(accM, ah, bl0);
  ld_a4(ah, pAh, 7);
  mm8(accM, al, bh0);
  ld_a4(al, pAl, 7);
  mm8(accH, ah, bh1);
  mm8(accM, ah, bl1);
  mm8(accM, al, bh1);

  // epilogue: score = (16384*accH + 128*accM) * (2*S_A*invr) * (sB*invc) - cnsq
  float icv[2], cqv[2];
#pragma unroll
  for (int ni = 0; ni < 2; ++ni) {
    int col = nbc * 64 + wn * 32 + ni * 16 + c0;
    icv[ni] = invc[col] * sB[col];
    cqv[ni] = cnsq[col];
  }
  const float SA = S_A_NUM / 16256.0f;
#pragma unroll
  for (int mi = 0; mi < 4; ++mi) {
    float4 ir4 = *(const float4*)&invr[mb * 128 + wm * 64 + mi * 16 + q * 4];
    float irv[4] = {ir4.x, ir4.y, ir4.z, ir4.w};
#pragma unroll
    for (int rr = 0; rr < 4; ++rr) {
      float tir = 2.0f * SA * irv[rr];
      float b = NEG_INF, s = NEG_INF;
      int bi = 2147483647;
#pragma unroll
      for (int ni = 0; ni < 2; ++ni) {
        float hsum = 16384.0f * (float)accH[mi][ni][rr] +
                     128.0f * (float)accM[mi][ni][rr];
        float v = hsum * (tir * icv[ni]) - cqv[ni];
        int col = nbc * 64 + wn * 32 + ni * 16 + c0;
        if (v > b) { s = b; b = v; bi = col; } else { s = fmaxf(s, v); }
      }
#pragma unroll
      for (int off = 1; off < 16; off <<= 1) {
        float ob = __shfl_xor(b, off, 64);
        float os = __shfl_xor(s, off, 64);
        int   oi = __shfl_xor(bi, off, 64);
        if (ob > b || (ob == b && oi < bi)) {
          s = fmaxf(b, os); b = ob; bi = oi;
        } else {
          s = fmaxf(s, ob);
        }
      }
      if (c0 == 0) {
        int rl = wm * 64 + mi * 16 + q * 4 + rr;  // 0..127 within block
        msb[wn][rl] = b;
        mss[wn][rl] = s;
        msi[wn][rl] = bi;
      }
    }
  }
  __syncthreads();
  if (tid < 128) {
    float B = msb[0][tid], S = mss[0][tid];
    int   I = msi[0][tid];
    float b1 = msb[1][tid], s1 = mss[1][tid];
    int   i1 = msi[1][tid];
    if (b1 > B || (b1 == B && i1 < I)) {
      S = fmaxf(s1, B); B = b1; I = i1;
    } else {
      S = fmaxf(S, b1);
    }
    size_t o = (size_t)(mb * 128 + tid) * 64 + nbc;
    candb[o] = B; cands2[o] = S; candi[o] = I;
  }
}

// ---------------------------------------------------------------- combine
// Global top-2 merge across the 64 col-groups; writes out, the quantized
// global best (bqv, used by the fix filter), and the fixlist trigger.
__global__ __launch_bounds__(256) void combine2_kernel(
    const float* __restrict__ candb, const float* __restrict__ cands2,
    const int* __restrict__ candi, int* __restrict__ out,
    float* __restrict__ bqv, int* __restrict__ fixlist,
    int* __restrict__ fixcount) {
  int r = blockIdx.x * 256 + threadIdx.x;
  float b = NEG_INF, s = NEG_INF;
  int bi = 2147483647;
  const float* pb = candb + (size_t)r * 64;
  const float* ps = cands2 + (size_t)r * 64;
  const int*   pi = candi + (size_t)r * 64;
#pragma unroll 4
  for (int j = 0; j < 64; ++j) {
    float cb_ = pb[j], cs_ = ps[j];
    int ci_ = pi[j];
    if (cb_ > b || (cb_ == b && ci_ < bi)) {
      s = fmaxf(b, cs_); b = cb_; bi = ci_;
    } else {
      s = fmaxf(s, cb_);
    }
  }
  out[r] = bi;
  bqv[r] = b;
  if (b - s < TAU_FIX) {
    int p = atomicAdd(fixcount, 1);
    if (p < M_ROWS) fixlist[p] = r;
  }
}

// ---------------------------------------------------------------- fixup
// Block-filtered exact rescan: one wave per fix row.  The true argmax's
// quantized score is >= global_best - 16*sigma (sigma ~1e-5 << TAU/16), so
// its 64-code group must have candb >= bqv - TAU.  Rescan only those groups
// (typically 1-2 of 64) with exact fp32 dots; ascending k + strict '>'
// preserves the min-k tie rule.  Direct out[] write (one wave owns the row).
__global__ __launch_bounds__(256) void fix_exact_kernel(
    const float* __restrict__ proj, const float* __restrict__ CB,
    const float* __restrict__ invr, const float* __restrict__ invc,
    const float* __restrict__ cnsq, const float* __restrict__ candb,
    const float* __restrict__ bqv, const int* __restrict__ fixlist,
    const int* __restrict__ fixcount, int* __restrict__ out) {
  int n = *fixcount;
  if (n > M_ROWS) n = M_ROWS;
  int nwaves = gridDim.x * 4;
  int gw = blockIdx.x * 4 + (threadIdx.x >> 6);
  int lane = threadIdx.x & 63;
  for (int it = gw; it < n; it += nwaves) {
    int r = fixlist[it];
    const float* pr = proj + (size_t)r * E_DIM + lane * 8;
    float4 p0 = *(const float4*)pr;
    float4 p1 = *(const float4*)(pr + 4);
    float tir = 2.0f * invr[r];
    float thresh = bqv[r] - TAU_FIX;
    const float* cbrow = candb + (size_t)r * 64;
    float best = NEG_INF;
    int bi = 2147483647;
    for (int g = 0; g < 64; ++g) {
      if (cbrow[g] < thresh) continue;
      int k0 = g * 64;
#pragma unroll 2
      for (int k = k0; k < k0 + 64; ++k) {
        const float* cr = CB + (size_t)k * E_DIM + lane * 8;
        float4 c0 = *(const float4*)cr;
        float4 c1 = *(const float4*)(cr + 4);
        float t = 0.f;
        t = fmaf(c0.x, p0.x, t); t = fmaf(c0.y, p0.y, t);
        t = fmaf(c0.z, p0.z, t); t = fmaf(c0.w, p0.w, t);
        t = fmaf(c1.x, p1.x, t); t = fmaf(c1.y, p1.y, t);
        t = fmaf(c1.z, p1.z, t); t = fmaf(c1.w, p1.w, t);
#pragma unroll
        for (int m = 1; m < 64; m <<= 1) t += __shfl_xor(t, m, 64);
        float sc = tir * invc[k] * t - cnsq[k];
        if (sc > best) { best = sc; bi = k; }
      }
    }
    if (lane == 0) out[r] = bi;
  }
}

// ================================================================ fallback
__global__ __launch_bounds__(256, 2) void gemm1_kernel(
    const float* __restrict__ A, const float* __restrict__ Bm,
    float* __restrict__ C) {
  __shared__ float As[2][16][132];
  __shared__ float Bs[2][16][128];
  int tid = threadIdx.x;
  int tx = tid & 15, ty = tid >> 4;
  int n0 = blockIdx.x * 128;
  int m0 = blockIdx.y * 128;

  int arow = tid >> 2;
  int akq  = (tid & 3) * 4;
  int bk   = tid >> 5;
  int bcol = (tid & 31) * 4;

  const float* Aptr  = A + (size_t)(m0 + arow) * D_DIM + akq;
  const float* Aptr2 = Aptr + (size_t)64 * D_DIM;
  const float* Bptr  = Bm + (size_t)bk * E_DIM + n0 + bcol;
  const float* Bptr2 = Bptr + (size_t)8 * E_DIM;

  float acc[8][8] = {};
  float4 a0 = *(const float4*)(Aptr);
  float4 a1 = *(const float4*)(Aptr2);
  float4 b0 = *(const float4*)(Bptr);
  float4 b1 = *(const float4*)(Bptr2);

  int buf = 0;
  for (int k0 = 0; k0 < D_DIM; k0 += 16) {
    As[buf][akq + 0][arow] = a0.x;
    As[buf][akq + 1][arow] = a0.y;
    As[buf][akq + 2][arow] = a0.z;
    As[buf][akq + 3][arow] = a0.w;
    As[buf][akq + 0][arow + 64] = a1.x;
    As[buf][akq + 1][arow + 64] = a1.y;
    As[buf][akq + 2][arow + 64] = a1.z;
    As[buf][akq + 3][arow + 64] = a1.w;
    *(float4*)&Bs[buf][bk][bcol]     = b0;
    *(float4*)&Bs[buf][bk + 8][bcol] = b1;
    __syncthreads();
    if (k0 + 16 < D_DIM) {
      a0 = *(const float4*)(Aptr + k0 + 16);
      a1 = *(const float4*)(Aptr2 + k0 + 16);
      b0 = *(const float4*)(Bptr + (size_t)(k0 + 16) * E_DIM);
      b1 = *(const float4*)(Bptr2 + (size_t)(k0 + 16) * E_DIM);
    }
#pragma unroll
    for (int kk = 0; kk < 16; ++kk) {
      float4 av0 = *(const float4*)&As[buf][kk][ty * 8];
      float4 av1 = *(const float4*)&As[buf][kk][ty * 8 + 4];
      float4 bv0 = *(const float4*)&Bs[buf][kk][tx * 4];
      float4 bv1 = *(const float4*)&Bs[buf][kk][tx * 4 + 64];
      float a[8] = {av0.x, av0.y, av0.z, av0.w, av1.x, av1.y, av1.z, av1.w};
      float b[8] = {bv0.x, bv0.y, bv0.z, bv0.w, bv1.x, bv1.y, bv1.z, bv1.w};
#pragma unroll
      for (int i = 0; i < 8; ++i)
#pragma unroll
        for (int j = 0; j < 8; ++j) acc[i][j] = fmaf(a[i], b[j], acc[i][j]);
    }
    buf ^= 1;
  }
#pragma unroll
  for (int i = 0; i < 8; ++i) {
    float* crow = C + (size_t)(m0 + ty * 8 + i) * E_DIM + n0;
    *(float4*)(crow + tx * 4)      = make_float4(acc[i][0], acc[i][1], acc[i][2], acc[i][3]);
    *(float4*)(crow + tx * 4 + 64) = make_float4(acc[i][4], acc[i][5], acc[i][6], acc[i][7]);
  }
}

__global__ __launch_bounds__(256, 2) void argmax_kernel(
    const float* __restrict__ P, const float* __restrict__ CB,
    const float* __restrict__ invr, const float* __restrict__ invc,
    const float* __restrict__ cnsq, float* __restrict__ cand_s,
    int* __restrict__ cand_i) {
  __shared__ float As[2][16][68];
  __shared__ float Bs[2][16][256];
  __shared__ float invr_s[64];
  __shared__ float red_s[64][33];
  __shared__ int   red_i[64][33];

  int tid = threadIdx.x;
  int tx = tid & 31, ty = tid >> 5;
  int m0 = blockIdx.x * 64;
  int cbase = blockIdx.y * 2048;
  if (tid < 64) invr_s[tid] = invr[m0 + tid];
  int arow = tid >> 2;
  int akq  = (tid & 3) * 4;
  const float* Aptr = P + (size_t)(m0 + arow) * E_DIM + akq;

  float best[8];
  int   bidx[8];
#pragma unroll
  for (int i = 0; i < 8; ++i) { best[i] = NEG_INF; bidx[i] = 0; }

  for (int n0 = 0; n0 < 2048; n0 += 256) {
    const float* Bptr = CB + (size_t)(cbase + n0 + tid) * E_DIM;
    float4 a0 = *(const float4*)(Aptr);
    float4 b0 = *(const float4*)(Bptr + 0);
    float4 b1 = *(const float4*)(Bptr + 4);
    float4 b2 = *(const float4*)(Bptr + 8);
    float4 b3 = *(const float4*)(Bptr + 12);
    float acc[8][8] = {};
    int buf = 0;
    for (int k0 = 0; k0 < E_DIM; k0 += 16) {
      As[buf][akq + 0][arow] = a0.x;
      As[buf][akq + 1][arow] = a0.y;
      As[buf][akq + 2][arow] = a0.z;
      As[buf][akq + 3][arow] = a0.w;
      Bs[buf][0][tid] = b0.x;  Bs[buf][1][tid] = b0.y;
      Bs[buf][2][tid] = b0.z;  Bs[buf][3][tid] = b0.w;
      Bs[buf][4][tid] = b1.x;  Bs[buf][5][tid] = b1.y;
      Bs[buf][6][tid] = b1.z;  Bs[buf][7][tid] = b1.w;
      Bs[buf][8][tid] = b2.x;  Bs[buf][9][tid] = b2.y;
      Bs[buf][10][tid] = b2.z; Bs[buf][11][tid] = b2.w;
      Bs[buf][12][tid] = b3.x; Bs[buf][13][tid] = b3.y;
      Bs[buf][14][tid] = b3.z; Bs[buf][15][tid] = b3.w;
      __syncthreads();
      if (k0 + 16 < E_DIM) {
        a0 = *(const float4*)(Aptr + k0 + 16);
        b0 = *(const float4*)(Bptr + k0 + 16);
        b1 = *(const float4*)(Bptr + k0 + 20);
        b2 = *(const float4*)(Bptr + k0 + 24);
        b3 = *(const float4*)(Bptr + k0 + 28);
      }
#pragma unroll
      for (int kk = 0; kk < 16; ++kk) {
        float4 av0 = *(const float4*)&As[buf][kk][ty * 8];
        float4 av1 = *(const float4*)&As[buf][kk][ty * 8 + 4];
        float4 bv0 = *(const float4*)&Bs[buf][kk][tx * 4];
        float4 bv1 = *(const float4*)&Bs[buf][kk][tx * 4 + 128];
        float a[8] = {av0.x, av0.y, av0.z, av0.w, av1.x, av1.y, av1.z, av1.w};
        float b[8] = {bv0.x, bv0.y, bv0.z, bv0.w, bv1.x, bv1.y, bv1.z, bv1.w};
#pragma unroll
        for (int i = 0; i < 8; ++i)
#pragma unroll
          for (int j = 0; j < 8; ++j) acc[i][j] = fmaf(a[i], b[j], acc[i][j]);
      }
      buf ^= 1;
    }
#pragma unroll
    for (int j4 = 0; j4 < 2; ++j4) {
      int nbq = cbase + n0 + j4 * 128 + tx * 4;
      float4 ic = *(const float4*)&invc[nbq];
      float4 cq = *(const float4*)&cnsq[nbq];
      float icv[4] = {ic.x, ic.y, ic.z, ic.w};
      float cqv[4] = {cq.x, cq.y, cq.z, cq.w};
#pragma unroll
      for (int i = 0; i < 8; ++i) {
        float ir2 = 2.0f * invr_s[ty * 8 + i];
#pragma unroll
        for (int jj = 0; jj < 4; ++jj) {
          float sc = acc[i][j4 * 4 + jj] * ir2 * icv[jj] - cqv[jj];
          if (sc > best[i]) { best[i] = sc; bidx[i] = nbq + jj; }
        }
      }
    }
  }
  __syncthreads();
#pragma unroll
  for (int i = 0; i < 8; ++i) {
    red_s[ty * 8 + i][tx] = best[i];
    red_i[ty * 8 + i][tx] = bidx[i];
  }
  __syncthreads();
  if (tid < 64) {
    float bs = red_s[tid][0];
    int bi = red_i[tid][0];
#pragma unroll
    for (int t = 1; t < 32; ++t) {
      float s = red_s[tid][t];
      int ii = red_i[tid][t];
      if (s > bs || (s == bs && ii < bi)) { bs = s; bi = ii; }
    }
    cand_s[(size_t)(m0 + tid) * 2 + blockIdx.y] = bs;
    cand_i[(size_t)(m0 + tid) * 2 + blockIdx.y] = bi;
  }
}

__global__ __launch_bounds__(256) void combine_kernel(
    const float* __restrict__ cand_s, const int* __restrict__ cand_i,
    int* __restrict__ out) {
  int r = blockIdx.x * 256 + threadIdx.x;
  float s0 = cand_s[r * 2], s1 = cand_s[r * 2 + 1];
  int i0 = cand_i[r * 2], i1 = cand_i[r * 2 + 1];
  out[r] = (s1 > s0 || (s1 == s0 && i1 < i0)) ? i1 : i0;
}

// ---------------------------------------------------------------- launch
extern "C" void kernel_launch(void* const* d_in, const int* in_sizes, int n_in,
                              void* d_out, int out_size, void* d_ws, size_t ws_size,
                              hipStream_t stream) {
  const float* x  = (const float*)d_in[0];
  const float* rp = (const float*)d_in[1];
  const float* cb = (const float*)d_in[2];
  int* out = (int*)d_out;

  char* w = (char*)d_ws;
  float* proj = (float*)w;        w += (size_t)M_ROWS * E_DIM * 4;   // 32 MB
  signed char* Ahq = (signed char*)w; w += (size_t)M_ROWS * E_DIM;   // 8 MB
  signed char* Alq = (signed char*)w; w += (size_t)M_ROWS * E_DIM;   // 8 MB
  signed char* Bhq = (signed char*)w; w += (size_t)K_CB * E_DIM;     // 2 MB
  signed char* Blq = (signed char*)w; w += (size_t)K_CB * E_DIM;     // 2 MB
  float* invr = (float*)w;        w += M_ROWS * 4;
  float* invc = (float*)w;        w += K_CB * 4;
  float* cnsq = (float*)w;        w += K_CB * 4;
  float* sB   = (float*)w;        w += K_CB * 4;
  float* candb  = (float*)w;      w += (size_t)M_ROWS * 64 * 4;      // 4 MB
  float* cands2 = (float*)w;      w += (size_t)M_ROWS * 64 * 4;      // 4 MB
  int*   candi  = (int*)w;        w += (size_t)M_ROWS * 64 * 4;      // 4 MB
  float* bqv  = (float*)w;        w += M_ROWS * 4;
  int*   fixlist  = (int*)w;      w += M_ROWS * 4;
  int*   fixcount = (int*)w;      w += 64;
  size_t need = (size_t)(w - (char*)d_ws);
  short* Ph = (short*)candb;      // overlay: dead until mfma_argmax writes
  short* Pl = (short*)cands2;

  if (ws_size >= need) {
    cbnorm_split_kernel<<<K_CB / 4, 256, 0, stream>>>(cb, invc, cnsq, sB, Bhq,
                                                      Blq, fixcount);
    psplit_kernel<<<64, 256, 0, stream>>>(rp, Ph, Pl);
    gemm1_mfma_kernel<<<dim3(E_DIM / 128, M_ROWS / 128), 256, 0, stream>>>(
        x, Ph, Pl, proj, Ahq, Alq);
    row_norm_kernel<<<M_ROWS / 4, 256, 0, stream>>>(proj, invr, nullptr, nullptr);
    mfma_argmax_kernel<<<(M_ROWS / 128) * (K_CB / 64), 256, 0, stream>>>(
        Ahq, Alq, Bhq, Blq, invr, invc, cnsq, sB, candb, cands2, candi);
    combine2_kernel<<<M_ROWS / 256, 256, 0, stream>>>(
        candb, cands2, candi, out, bqv, fixlist, fixcount);
    fix_exact_kernel<<<256, 256, 0, stream>>>(
        proj, cb, invr, invc, cnsq, candb, bqv, fixlist, fixcount, out);
  } else {
    float* ws    = (float*)d_ws;
    float* proj1 = ws;
    float* invr1 = proj1 + (size_t)M_ROWS * E_DIM;
    float* invc1 = invr1 + M_ROWS;
    float* cnsq1 = invc1 + K_CB;
    float* cands = cnsq1 + K_CB;
    int*   candi1 = (int*)(cands + (size_t)M_ROWS * 2);

    row_norm_kernel<<<K_CB / 4, 256, 0, stream>>>(cb, invc1, cnsq1, nullptr);
    gemm1_kernel<<<dim3(E_DIM / 128, M_ROWS / 128), 256, 0, stream>>>(x, rp, proj1);
    row_norm_kernel<<<M_ROWS / 4, 256, 0, stream>>>(proj1, invr1, nullptr, nullptr);
    argmax_kernel<<<dim3(M_ROWS / 64, 2), 256, 0, stream>>>(proj1, cb, invr1,
                                                            invc1, cnsq1, cands, candi1);
    combine_kernel<<<M_ROWS / 256, 256, 0, stream>>>(cands, candi1, out);
  }
}

// Round 8
// 434.487 us; speedup vs baseline: 1.0683x; 1.0683x over previous
//
#include <hip/hip_runtime.h>
#include <hip/hip_bf16.h>

// Problem: RandomProjectionQuantizer  B=4 N=4096 D=1024 E=512 K=4096
// M = B*N = 16384 rows.
// proj = X @ P (fp32), scores = 2*invr_m*invc_k*(cb_k . proj_m) - cnsq_k,
// nearest = argmax_k score (ties -> min k).
// Round 19: r14-exact argmax + TRANSPOSED cand layout.
// r18 refuted the occupancy lever (3 waves/SIMD, -36%): the argmax is
// operand-delivery-bound per byte; r14 (173us) is the proven best loop.
// New counter evidence: argmax WRITE_SIZE = 49 MB/dispatch vs 6 MB useful
// cand data (98 MB in r18's 64-group variant - scales with cand size).
// The epilogue's candb[row*32+nb] scatter puts one 4B store per 128B line
// -> ~8x L2 partial-line write amplification.  Fix: cand arrays become
// [nb][row] - argmax writes 512B contiguous runs, combine2 reads 1KB
// coalesced runs, fix_exact's filter does 32 L2-hit scalar loads.

#define M_ROWS 16384
#define D_DIM  1024
#define E_DIM  512
#define K_CB   4096
#define EPS_N  1e-12f
#define TAU_FIX 4e-4f
#define NEG_INF (-3.4e38f)
#define S_A_NUM 12.0f   // fixed A-scale: proj elem std ~1.155, 12.0 ~ 10.4 sigma

typedef short bf16x8 __attribute__((ext_vector_type(8)));
typedef _Float16 f16x8 __attribute__((ext_vector_type(8)));
typedef short s16x4 __attribute__((ext_vector_type(4)));
typedef float f32x4  __attribute__((ext_vector_type(4)));
typedef int   i32x4  __attribute__((ext_vector_type(4)));

// ---------------------------------------------------------------- helpers
__device__ __forceinline__ unsigned short f32_to_bf16_rtne(float x) {
  unsigned u = __float_as_uint(x);
  unsigned r = u + 0x7FFFu + ((u >> 16) & 1u);
  return (unsigned short)(r >> 16);
}
__device__ __forceinline__ float bf16_bits_to_f32(unsigned short h) {
  return __uint_as_float(((unsigned)h) << 16);
}
__device__ __forceinline__ void split_f16(float x, short& hs, short& ls) {
  _Float16 h = (_Float16)x;
  float hf = (float)h;
  _Float16 l = (_Float16)(x - hf);
  hs = __builtin_bit_cast(short, h);
  ls = __builtin_bit_cast(short, l);
}
__device__ __forceinline__ void g2l16(const void* g, void* l) {
  __builtin_amdgcn_global_load_lds(
      (const __attribute__((address_space(1))) unsigned*)g,
      (__attribute__((address_space(3))) unsigned*)l, 16, 0, 0);
}
__device__ __forceinline__ i32x4 mfma_i8(i32x4 a, i32x4 b, i32x4 c) {
  return __builtin_amdgcn_mfma_i32_16x16x64_i8(a, b, c, 0, 0, 0);
}
// quantize x (already scaled to q-units, |q|<=16256) into h,l int8
__device__ __forceinline__ void split_i8(float qv, signed char& h,
                                         signed char& l) {
  float hf = rintf(qv * (1.0f / 128.0f));
  float lf = qv - 128.0f * hf;
  h = (signed char)(int)hf;
  l = (signed char)(int)lf;
}

// ---------------------------------------------------------------- row norms
__global__ __launch_bounds__(256) void row_norm_kernel(
    const float* __restrict__ src, float* __restrict__ inv_out,
    float* __restrict__ sq_out, int* __restrict__ zero_me) {
  if (zero_me && blockIdx.x == 0 && threadIdx.x == 0) *zero_me = 0;
  int row  = blockIdx.x * 4 + (threadIdx.x >> 6);
  int lane = threadIdx.x & 63;
  const float4* p = (const float4*)(src + (size_t)row * E_DIM);
  float4 v0 = p[lane];
  float4 v1 = p[lane + 64];
  float s = v0.x * v0.x + v0.y * v0.y + v0.z * v0.z + v0.w * v0.w +
            v1.x * v1.x + v1.y * v1.y + v1.z * v1.z + v1.w * v1.w;
#pragma unroll
  for (int m = 32; m; m >>= 1) s += __shfl_xor(s, m, 64);
  float d = fmaxf(sqrtf(s), EPS_N);
  if (sq_out) {
    float q0 = v0.x / d, q1 = v0.y / d, q2 = v0.z / d, q3 = v0.w / d;
    float q4 = v1.x / d, q5 = v1.y / d, q6 = v1.z / d, q7 = v1.w / d;
    float q = q0 * q0 + q1 * q1 + q2 * q2 + q3 * q3 +
              q4 * q4 + q5 * q5 + q6 * q6 + q7 * q7;
#pragma unroll
    for (int m = 32; m; m >>= 1) q += __shfl_xor(q, m, 64);
    if (lane == 0) sq_out[row] = q;
  }
  if (lane == 0) inv_out[row] = 1.0f / d;
}

// ---------------------------------------------------------------- cb norm+split
// Per codebook row: invc, cnsq, per-row i8 scale sB, and i8 h/l fragments in
// mfma_i32_16x16x64_i8 B-layout: byte idx =
// ((nb*8 + kc8)*512 + q*128 + row128)*16 + j16, kc8=k>>6, q=(k&63)>>4, j16=k&15.
__global__ __launch_bounds__(256) void cbnorm_split_kernel(
    const float* __restrict__ cb, float* __restrict__ invc,
    float* __restrict__ cnsq, float* __restrict__ sB,
    signed char* __restrict__ Bhq, signed char* __restrict__ Blq,
    int* __restrict__ zero_me) {
  if (zero_me && blockIdx.x == 0 && threadIdx.x == 0) *zero_me = 0;
  int r    = blockIdx.x * 4 + (threadIdx.x >> 6);
  int lane = threadIdx.x & 63;
  const float* src = cb + (size_t)r * E_DIM + lane * 8;
  float4 v0 = *(const float4*)src;
  float4 v1 = *(const float4*)(src + 4);
  float v[8] = {v0.x, v0.y, v0.z, v0.w, v1.x, v1.y, v1.z, v1.w};
  float s = 0.f;
#pragma unroll
  for (int j = 0; j < 8; ++j) s = fmaf(v[j], v[j], s);
#pragma unroll
  for (int m = 32; m; m >>= 1) s += __shfl_xor(s, m, 64);
  float d = fmaxf(sqrtf(s), EPS_N);
  float q = 0.f;
#pragma unroll
  for (int j = 0; j < 8; ++j) { float t = v[j] / d; q = fmaf(t, t, q); }
#pragma unroll
  for (int m = 32; m; m >>= 1) q += __shfl_xor(q, m, 64);
  float am = 0.f;
#pragma unroll
  for (int j = 0; j < 8; ++j) am = fmaxf(am, fabsf(v[j]));
#pragma unroll
  for (int m = 32; m; m >>= 1) am = fmaxf(am, __shfl_xor(am, m, 64));
  float inv_sb = (am > 0.f) ? (16256.0f / am) : 0.0f;
  if (lane == 0) {
    cnsq[r] = q;
    invc[r] = 1.0f / d;
    sB[r] = (am > 0.f) ? (am / 16256.0f) : 0.0f;
  }
  union { signed char c8[8]; uint2 u; } Hq, Lq;
#pragma unroll
  for (int j = 0; j < 8; ++j) {
    float qv = rintf(v[j] * inv_sb);  // |qv| <= 16256 by construction
    split_i8(qv, Hq.c8[j], Lq.c8[j]);
  }
  int nb = r >> 7, row = r & 127;
  int kc8 = lane >> 3, qq = (lane & 7) >> 1, jh = lane & 1;
  size_t idx = (((size_t)(nb * 8 + kc8) * 512) + qq * 128 + row) * 16 + jh * 8;
  *(uint2*)(Bhq + idx) = Hq.u;
  *(uint2*)(Blq + idx) = Lq.u;
}

// ---------------------------------------------------------------- P split
__global__ __launch_bounds__(256) void psplit_kernel(
    const float* __restrict__ P, short* __restrict__ Ph,
    short* __restrict__ Pl) {
  int tid = threadIdx.x;
#pragma unroll
  for (int i = 0; i < 4; ++i) {
    int g = blockIdx.x * 1024 + i * 256 + tid;  // 0..65535
    int k8 = g >> 9, col = g & 511;
    int nb = col >> 7, c = col & 127;
    int kc = k8 >> 2, q = k8 & 3;
    union { short s8[8]; float4 f; } H, L;
#pragma unroll
    for (int j = 0; j < 8; ++j) {
      float v = P[(size_t)(k8 * 8 + j) * 512 + col] * 4096.0f;
      split_f16(v, H.s8[j], L.s8[j]);
    }
    size_t dst = (((size_t)(nb * 32 + kc) * 4 + q) * 128 + c) * 8;
    *(float4*)(Ph + dst) = H.f;
    *(float4*)(Pl + dst) = L.f;
  }
}

// ---------------------------------------------------------------- GEMM1 (MFMA)
// proj = X @ P via fp16-split MFMA (hh+hl+lh), scale 4096^2 backed out.
// Epilogue writes proj fp32 + i8 h/l A-fragments (fixed scale 12/16256) in
// mfma_i32_16x16x64_i8 A-layout.
__global__ __launch_bounds__(256, 2) void gemm1_mfma_kernel(
    const float* __restrict__ X, const short* __restrict__ Ph,
    const short* __restrict__ Pl, float* __restrict__ proj,
    signed char* __restrict__ Ahq, signed char* __restrict__ Alq) {
  __shared__ short lds_ah[4096];
  __shared__ short lds_al[4096];
  __shared__ short lds_bh[4096];
  __shared__ short lds_bl[4096];
  int tid = threadIdx.x;
  int wid = tid >> 6, lane = tid & 63;
  int nb = blockIdx.x, mb = blockIdx.y;
  int m0 = mb * 128, n0 = nb * 128;
  int wm = wid >> 1, wn = wid & 1;
  int q4 = lane >> 4, c0 = lane & 15;

  f32x4 zero = {0.f, 0.f, 0.f, 0.f};
  f32x4 acc[4][4];
#pragma unroll
  for (int i = 0; i < 4; ++i)
#pragma unroll
    for (int j = 0; j < 4; ++j) acc[i][j] = zero;

  for (int kc = 0; kc < 32; ++kc) {
    const char* gb = (const char*)Ph + ((size_t)(nb * 32 + kc)) * 8192;
    const char* gl = (const char*)Pl + ((size_t)(nb * 32 + kc)) * 8192;
#pragma unroll
    for (int p = 0; p < 4; ++p) {
      int s = wid * 4 + p;
      int t = s >> 3;
      int off = (s & 7) * 1024;
      const char* src = (t == 0 ? gb : gl) + off + lane * 16;
      char* dst = (char*)(t == 0 ? lds_bh : lds_bl) + off;
      g2l16(src, dst);
    }
#pragma unroll
    for (int i = 0; i < 4; ++i) {
      int e = i * 1024 + tid * 4;
      int row = e >> 5, k4 = e & 31;
      int q = k4 >> 3, j0 = k4 & 7;
      float4 xv = *(const float4*)(X + (size_t)(m0 + row) * D_DIM + kc * 32 + k4);
      float v[4] = {xv.x * 4096.f, xv.y * 4096.f, xv.z * 4096.f, xv.w * 4096.f};
      s16x4 H, L;
#pragma unroll
      for (int j = 0; j < 4; ++j) {
        short hs, ls;
        split_f16(v[j], hs, ls);
        H[j] = hs; L[j] = ls;
      }
      int o = (q * 128 + row) * 8 + j0;
      *(s16x4*)&lds_ah[o] = H;
      *(s16x4*)&lds_al[o] = L;
    }
    __syncthreads();

    f16x8 bh[4], bl[4];
#pragma unroll
    for (int ni = 0; ni < 4; ++ni) {
      int boff = (q4 * 128 + wn * 64 + ni * 16 + c0) * 8;
      bh[ni] = *(const f16x8*)&lds_bh[boff];
      bl[ni] = *(const f16x8*)&lds_bl[boff];
    }
#pragma unroll
    for (int mi = 0; mi < 4; ++mi) {
      int aoff = (q4 * 128 + wm * 64 + mi * 16 + c0) * 8;
      f16x8 ah = *(const f16x8*)&lds_ah[aoff];
      f16x8 al = *(const f16x8*)&lds_al[aoff];
#pragma unroll
      for (int ni = 0; ni < 4; ++ni) {
        acc[mi][ni] = __builtin_amdgcn_mfma_f32_16x16x32_f16(
            ah, bh[ni], acc[mi][ni], 0, 0, 0);
        acc[mi][ni] = __builtin_amdgcn_mfma_f32_16x16x32_f16(
            ah, bl[ni], acc[mi][ni], 0, 0, 0);
        acc[mi][ni] = __builtin_amdgcn_mfma_f32_16x16x32_f16(
            al, bh[ni], acc[mi][ni], 0, 0, 0);
      }
    }
    __syncthreads();
  }

  const float inv_s = 1.0f / 16777216.0f;
  const float QA = 16256.0f / S_A_NUM;
#pragma unroll
  for (int ni = 0; ni < 4; ++ni) {
    int gcol = n0 + wn * 64 + ni * 16 + c0;
    int kc8 = gcol >> 6, qe = (gcol & 63) >> 4, je = gcol & 15;
    size_t ibase = (((size_t)(mb * 8 + kc8) * 512) + qe * 128) * 16 + je;
#pragma unroll
    for (int mi = 0; mi < 4; ++mi) {
#pragma unroll
      for (int r = 0; r < 4; ++r) {
        int rl = wm * 64 + mi * 16 + q4 * 4 + r;
        float val = acc[mi][ni][r] * inv_s;
        proj[(size_t)(m0 + rl) * E_DIM + gcol] = val;
        float qv = rintf(fminf(fmaxf(val * QA, -16256.f), 16256.f));
        signed char hq, lq;
        split_i8(qv, hq, lq);
        size_t idx = ibase + (size_t)rl * 16;
        Ahq[idx] = hq;
        Alq[idx] = lq;
      }
    }
  }
}

// ---------------------------------------------------------------- MFMA argmax
// INT8 register-pipelined LDS-free K-loop (r14-exact structure, 173us).
// Grid 4096 linear, swizzled into 4mb x 8nb tiles (mb 0..127, nb 0..31).
// Block tile 128x128, 4 waves 2x2, wave tile 64x64.
// Per K-chunk (K=64): 3 passes of 16 mfma_i32_16x16x64_i8:
//   accH += h_a.h_b ; accM += h_a.l_b ; accM += l_a.h_b   (l.l dropped)
// B-fragments double-buffered across chunks; A-fragments reloaded mid-chunk
// right after their last use.  No LDS, no barriers in the K-loop.
// Cand output layout is TRANSPOSED [nb][row] for coalesced 512B runs
// (r18 counter evidence: [row][nb] scatter caused ~8x write amplification,
// WRITE_SIZE 49MB vs 6MB useful).
__device__ __forceinline__ void ld_bset(i32x4 (&bh)[4], i32x4 (&bl)[4],
                                        const char* pBh, const char* pBl,
                                        int kc) {
#pragma unroll
  for (int ni = 0; ni < 4; ++ni) {
    bh[ni] = *(const i32x4*)(pBh + kc * 8192 + ni * 256);
    bl[ni] = *(const i32x4*)(pBl + kc * 8192 + ni * 256);
  }
}
__device__ __forceinline__ void ld_ah4(i32x4 (&ah)[4], const char* pAh, int kc) {
#pragma unroll
  for (int mi = 0; mi < 4; ++mi)
    ah[mi] = *(const i32x4*)(pAh + kc * 8192 + mi * 256);
}
__device__ __forceinline__ void ld_al4(i32x4 (&al)[4], const char* pAl, int kc) {
#pragma unroll
  for (int mi = 0; mi < 4; ++mi)
    al[mi] = *(const i32x4*)(pAl + kc * 8192 + mi * 256);
}

__device__ __forceinline__ void passes_i8(
    i32x4 (&accH)[4][4], i32x4 (&accM)[4][4], i32x4 (&ah)[4], i32x4 (&al)[4],
    const i32x4 (&bh)[4], const i32x4 (&bl)[4], const char* pAh,
    const char* pAl, int nkc, bool doA) {
#pragma unroll
  for (int mi = 0; mi < 4; ++mi)
#pragma unroll
    for (int ni = 0; ni < 4; ++ni)
      accH[mi][ni] = mfma_i8(ah[mi], bh[ni], accH[mi][ni]);
#pragma unroll
  for (int mi = 0; mi < 4; ++mi)
#pragma unroll
    for (int ni = 0; ni < 4; ++ni)
      accM[mi][ni] = mfma_i8(ah[mi], bl[ni], accM[mi][ni]);
  if (doA) ld_ah4(ah, pAh, nkc);   // ah dead after pass 2
#pragma unroll
  for (int mi = 0; mi < 4; ++mi)
#pragma unroll
    for (int ni = 0; ni < 4; ++ni)
      accM[mi][ni] = mfma_i8(al[mi], bh[ni], accM[mi][ni]);
  if (doA) ld_al4(al, pAl, nkc);   // al dead after pass 3
}

__global__ __launch_bounds__(256, 2) void mfma_argmax_kernel(
    const signed char* __restrict__ Ahq, const signed char* __restrict__ Alq,
    const signed char* __restrict__ Bhq, const signed char* __restrict__ Blq,
    const float* __restrict__ invr, const float* __restrict__ invc,
    const float* __restrict__ cnsq, const float* __restrict__ sB,
    float* __restrict__ candb, float* __restrict__ cands2,
    int* __restrict__ candi) {
  __shared__ float msb[256];
  __shared__ float mss[256];
  __shared__ int   msi[256];
  int tid = threadIdx.x;
  int wid = tid >> 6, lane = tid & 63;
  // swizzle: 32-block tiles of 4 mb x 8 nb for per-XCD L2 locality
  int lin = blockIdx.x;
  int tile = lin >> 5, wi = lin & 31;
  int tnb = tile & 3, tmb = tile >> 2;   // tnb 0..3, tmb 0..31
  int nb = tnb * 8 + (wi & 7);           // 0..31
  int mb = tmb * 4 + (wi >> 3);          // 0..127

  int wm = wid >> 1, wn = wid & 1;
  int q = lane >> 4, c0 = lane & 15;

  // per-lane fragment base pointers (byte units; 65536 B per 128-row panel)
  const char* pAh = (const char*)Ahq + (size_t)mb * 65536 +
                    (q * 128 + wm * 64 + c0) * 16;
  const char* pAl = (const char*)Alq + (size_t)mb * 65536 +
                    (q * 128 + wm * 64 + c0) * 16;
  const char* pBh = (const char*)Bhq + (size_t)nb * 65536 +
                    (q * 128 + wn * 64 + c0) * 16;
  const char* pBl = (const char*)Blq + (size_t)nb * 65536 +
                    (q * 128 + wn * 64 + c0) * 16;

  i32x4 zero = {0, 0, 0, 0};
  i32x4 accH[4][4], accM[4][4];
#pragma unroll
  for (int i = 0; i < 4; ++i)
#pragma unroll
    for (int j = 0; j < 4; ++j) { accH[i][j] = zero; accM[i][j] = zero; }

  i32x4 ah[4], al[4], bh0[4], bl0[4], bh1[4], bl1[4];
  ld_bset(bh0, bl0, pBh, pBl, 0);
  ld_ah4(ah, pAh, 0);
  ld_al4(al, pAl, 0);
  for (int t = 0; t < 6; t += 2) {
    ld_bset(bh1, bl1, pBh, pBl, t + 1);
    passes_i8(accH, accM, ah, al, bh0, bl0, pAh, pAl, t + 1, true);
    ld_bset(bh0, bl0, pBh, pBl, t + 2);
    passes_i8(accH, accM, ah, al, bh1, bl1, pAh, pAl, t + 2, true);
  }
  ld_bset(bh1, bl1, pBh, pBl, 7);
  passes_i8(accH, accM, ah, al, bh0, bl0, pAh, pAl, 7, true);   // chunk 6
  passes_i8(accH, accM, ah, al, bh1, bl1, pAh, pAl, 0, false);  // chunk 7

  // epilogue: score = (16384*accH + 128*accM) * (2*S_A*invr) * (sB*invc) - cnsq
  float icv[4], cqv[4];
#pragma unroll
  for (int ni = 0; ni < 4; ++ni) {
    int n = nb * 128 + wn * 64 + ni * 16 + c0;
    icv[ni] = invc[n] * sB[n];
    cqv[ni] = cnsq[n];
  }
  const float SA = S_A_NUM / 16256.0f;
#pragma unroll
  for (int mi = 0; mi < 4; ++mi) {
    float4 ir4 = *(const float4*)&invr[mb * 128 + wm * 64 + mi * 16 + q * 4];
    float irv[4] = {ir4.x, ir4.y, ir4.z, ir4.w};
#pragma unroll
    for (int r = 0; r < 4; ++r) {
      float tir = 2.0f * SA * irv[r];
      float b = NEG_INF, s = NEG_INF;
      int bi = 2147483647;
#pragma unroll
      for (int ni = 0; ni < 4; ++ni) {
        float hsum = 16384.0f * (float)accH[mi][ni][r] +
                     128.0f * (float)accM[mi][ni][r];
        float v = hsum * (tir * icv[ni]) - cqv[ni];
        int n = nb * 128 + wn * 64 + ni * 16 + c0;
        if (v > b) { s = b; b = v; bi = n; } else { s = fmaxf(s, v); }
      }
#pragma unroll
      for (int off = 1; off < 16; off <<= 1) {
        float ob = __shfl_xor(b, off, 64);
        float os = __shfl_xor(s, off, 64);
        int   oi = __shfl_xor(bi, off, 64);
        if (ob > b || (ob == b && oi < bi)) {
          s = fmaxf(b, os); b = ob; bi = oi;
        } else {
          s = fmaxf(s, ob);
        }
      }
      if (c0 == 0) {
        int rl = wm * 64 + mi * 16 + q * 4 + r;  // 0..127 within block
        msb[wn * 128 + rl] = b;
        mss[wn * 128 + rl] = s;
        msi[wn * 128 + rl] = bi;
      }
    }
  }
  __syncthreads();
  if (tid < 128) {
    float b0 = msb[tid],       s0 = mss[tid];
    float b1 = msb[128 + tid], s1 = mss[128 + tid];
    int   i0 = msi[tid],       i1 = msi[128 + tid];
    float B, S; int I;
    if (b1 > b0 || (b1 == b0 && i1 < i0)) {
      B = b1; S = fmaxf(s1, b0); I = i1;
    } else {
      B = b0; S = fmaxf(s0, b1); I = i0;
    }
    // TRANSPOSED cand layout: [nb][row] -> 512B contiguous runs
    size_t o = (size_t)nb * M_ROWS + mb * 128 + tid;
    candb[o] = B; cands2[o] = S; candi[o] = I;
  }
}

// ---------------------------------------------------------------- combine
// Global top-2 merge across the 32 nb-blocks; writes out, the quantized
// global best (bqv, used by the fix filter), and the fixlist trigger.
// Cand arrays are [nb][row]: per nb-iteration the 256 threads read 1KB
// coalesced runs.
__global__ __launch_bounds__(256) void combine2_kernel(
    const float* __restrict__ candb, const float* __restrict__ cands2,
    const int* __restrict__ candi, int* __restrict__ out,
    float* __restrict__ bqv, int* __restrict__ fixlist,
    int* __restrict__ fixcount) {
  int r = blockIdx.x * 256 + threadIdx.x;
  float b = NEG_INF, s = NEG_INF;
  int bi = 2147483647;
#pragma unroll 4
  for (int j = 0; j < 32; ++j) {
    size_t o = (size_t)j * M_ROWS + r;
    float cb_ = candb[o], cs_ = cands2[o];
    int ci_ = candi[o];
    if (cb_ > b || (cb_ == b && ci_ < bi)) {
      s = fmaxf(b, cs_); b = cb_; bi = ci_;
    } else {
      s = fmaxf(s, cb_);
    }
  }
  out[r] = bi;
  bqv[r] = b;
  if (b - s < TAU_FIX) {
    int p = atomicAdd(fixcount, 1);
    if (p < M_ROWS) fixlist[p] = r;
  }
}

// ---------------------------------------------------------------- fixup
// Block-filtered exact rescan: one wave per fix row.  The true argmax's
// quantized score is >= global_best - 16*sigma (sigma ~1e-5 << TAU/16), so
// its 128-code block must have candb >= bqv - TAU.  Rescan only those
// blocks (typically 1-2 of 32) with exact fp32 dots; ascending k + strict
// '>' preserves the min-k tie rule.  Direct out[] write (one wave owns the
// row; no race).
__global__ __launch_bounds__(256) void fix_exact_kernel(
    const float* __restrict__ proj, const float* __restrict__ CB,
    const float* __restrict__ invr, const float* __restrict__ invc,
    const float* __restrict__ cnsq, const float* __restrict__ candb,
    const float* __restrict__ bqv, const int* __restrict__ fixlist,
    const int* __restrict__ fixcount, int* __restrict__ out) {
  int n = *fixcount;
  if (n > M_ROWS) n = M_ROWS;
  int nwaves = gridDim.x * 4;
  int gw = blockIdx.x * 4 + (threadIdx.x >> 6);
  int lane = threadIdx.x & 63;
  for (int it = gw; it < n; it += nwaves) {
    int r = fixlist[it];
    const float* pr = proj + (size_t)r * E_DIM + lane * 8;
    float4 p0 = *(const float4*)pr;
    float4 p1 = *(const float4*)(pr + 4);
    float tir = 2.0f * invr[r];
    float thresh = bqv[r] - TAU_FIX;
    float best = NEG_INF;
    int bi = 2147483647;
    for (int nb = 0; nb < 32; ++nb) {
      if (candb[(size_t)nb * M_ROWS + r] < thresh) continue;
      int k0 = nb * 128;
#pragma unroll 2
      for (int k = k0; k < k0 + 128; ++k) {
        const float* cr = CB + (size_t)k * E_DIM + lane * 8;
        float4 c0 = *(const float4*)cr;
        float4 c1 = *(const float4*)(cr + 4);
        float t = 0.f;
        t = fmaf(c0.x, p0.x, t); t = fmaf(c0.y, p0.y, t);
        t = fmaf(c0.z, p0.z, t); t = fmaf(c0.w, p0.w, t);
        t = fmaf(c1.x, p1.x, t); t = fmaf(c1.y, p1.y, t);
        t = fmaf(c1.z, p1.z, t); t = fmaf(c1.w, p1.w, t);
#pragma unroll
        for (int m = 1; m < 64; m <<= 1) t += __shfl_xor(t, m, 64);
        float sc = tir * invc[k] * t - cnsq[k];
        if (sc > best) { best = sc; bi = k; }
      }
    }
    if (lane == 0) out[r] = bi;
  }
}

// ================================================================ fallback
__global__ __launch_bounds__(256, 2) void gemm1_kernel(
    const float* __restrict__ A, const float* __restrict__ Bm,
    float* __restrict__ C) {
  __shared__ float As[2][16][132];
  __shared__ float Bs[2][16][128];
  int tid = threadIdx.x;
  int tx = tid & 15, ty = tid >> 4;
  int n0 = blockIdx.x * 128;
  int m0 = blockIdx.y * 128;

  int arow = tid >> 2;
  int akq  = (tid & 3) * 4;
  int bk   = tid >> 5;
  int bcol = (tid & 31) * 4;

  const float* Aptr  = A + (size_t)(m0 + arow) * D_DIM + akq;
  const float* Aptr2 = Aptr + (size_t)64 * D_DIM;
  const float* Bptr  = Bm + (size_t)bk * E_DIM + n0 + bcol;
  const float* Bptr2 = Bptr + (size_t)8 * E_DIM;

  float acc[8][8] = {};
  float4 a0 = *(const float4*)(Aptr);
  float4 a1 = *(const float4*)(Aptr2);
  float4 b0 = *(const float4*)(Bptr);
  float4 b1 = *(const float4*)(Bptr2);

  int buf = 0;
  for (int k0 = 0; k0 < D_DIM; k0 += 16) {
    As[buf][akq + 0][arow] = a0.x;
    As[buf][akq + 1][arow] = a0.y;
    As[buf][akq + 2][arow] = a0.z;
    As[buf][akq + 3][arow] = a0.w;
    As[buf][akq + 0][arow + 64] = a1.x;
    As[buf][akq + 1][arow + 64] = a1.y;
    As[buf][akq + 2][arow + 64] = a1.z;
    As[buf][akq + 3][arow + 64] = a1.w;
    *(float4*)&Bs[buf][bk][bcol]     = b0;
    *(float4*)&Bs[buf][bk + 8][bcol] = b1;
    __syncthreads();
    if (k0 + 16 < D_DIM) {
      a0 = *(const float4*)(Aptr + k0 + 16);
      a1 = *(const float4*)(Aptr2 + k0 + 16);
      b0 = *(const float4*)(Bptr + (size_t)(k0 + 16) * E_DIM);
      b1 = *(const float4*)(Bptr2 + (size_t)(k0 + 16) * E_DIM);
    }
#pragma unroll
    for (int kk = 0; kk < 16; ++kk) {
      float4 av0 = *(const float4*)&As[buf][kk][ty * 8];
      float4 av1 = *(const float4*)&As[buf][kk][ty * 8 + 4];
      float4 bv0 = *(const float4*)&Bs[buf][kk][tx * 4];
      float4 bv1 = *(const float4*)&Bs[buf][kk][tx * 4 + 64];
      float a[8] = {av0.x, av0.y, av0.z, av0.w, av1.x, av1.y, av1.z, av1.w};
      float b[8] = {bv0.x, bv0.y, bv0.z, bv0.w, bv1.x, bv1.y, bv1.z, bv1.w};
#pragma unroll
      for (int i = 0; i < 8; ++i)
#pragma unroll
        for (int j = 0; j < 8; ++j) acc[i][j] = fmaf(a[i], b[j], acc[i][j]);
    }
    buf ^= 1;
  }
#pragma unroll
  for (int i = 0; i < 8; ++i) {
    float* crow = C + (size_t)(m0 + ty * 8 + i) * E_DIM + n0;
    *(float4*)(crow + tx * 4)      = make_float4(acc[i][0], acc[i][1], acc[i][2], acc[i][3]);
    *(float4*)(crow + tx * 4 + 64) = make_float4(acc[i][4], acc[i][5], acc[i][6], acc[i][7]);
  }
}

__global__ __launch_bounds__(256, 2) void argmax_kernel(
    const float* __restrict__ P, const float* __restrict__ CB,
    const float* __restrict__ invr, const float* __restrict__ invc,
    const float* __restrict__ cnsq, float* __restrict__ cand_s,
    int* __restrict__ cand_i) {
  __shared__ float As[2][16][68];
  __shared__ float Bs[2][16][256];
  __shared__ float invr_s[64];
  __shared__ float red_s[64][33];
  __shared__ int   red_i[64][33];

  int tid = threadIdx.x;
  int tx = tid & 31, ty = tid >> 5;
  int m0 = blockIdx.x * 64;
  int cbase = blockIdx.y * 2048;
  if (tid < 64) invr_s[tid] = invr[m0 + tid];
  int arow = tid >> 2;
  int akq  = (tid & 3) * 4;
  const float* Aptr = P + (size_t)(m0 + arow) * E_DIM + akq;

  float best[8];
  int   bidx[8];
#pragma unroll
  for (int i = 0; i < 8; ++i) { best[i] = NEG_INF; bidx[i] = 0; }

  for (int n0 = 0; n0 < 2048; n0 += 256) {
    const float* Bptr = CB + (size_t)(cbase + n0 + tid) * E_DIM;
    float4 a0 = *(const float4*)(Aptr);
    float4 b0 = *(const float4*)(Bptr + 0);
    float4 b1 = *(const float4*)(Bptr + 4);
    float4 b2 = *(const float4*)(Bptr + 8);
    float4 b3 = *(const float4*)(Bptr + 12);
    float acc[8][8] = {};
    int buf = 0;
    for (int k0 = 0; k0 < E_DIM; k0 += 16) {
      As[buf][akq + 0][arow] = a0.x;
      As[buf][akq + 1][arow] = a0.y;
      As[buf][akq + 2][arow] = a0.z;
      As[buf][akq + 3][arow] = a0.w;
      Bs[buf][0][tid] = b0.x;  Bs[buf][1][tid] = b0.y;
      Bs[buf][2][tid] = b0.z;  Bs[buf][3][tid] = b0.w;
      Bs[buf][4][tid] = b1.x;  Bs[buf][5][tid] = b1.y;
      Bs[buf][6][tid] = b1.z;  Bs[buf][7][tid] = b1.w;
      Bs[buf][8][tid] = b2.x;  Bs[buf][9][tid] = b2.y;
      Bs[buf][10][tid] = b2.z; Bs[buf][11][tid] = b2.w;
      Bs[buf][12][tid] = b3.x; Bs[buf][13][tid] = b3.y;
      Bs[buf][14][tid] = b3.z; Bs[buf][15][tid] = b3.w;
      __syncthreads();
      if (k0 + 16 < E_DIM) {
        a0 = *(const float4*)(Aptr + k0 + 16);
        b0 = *(const float4*)(Bptr + k0 + 16);
        b1 = *(const float4*)(Bptr + k0 + 20);
        b2 = *(const float4*)(Bptr + k0 + 24);
        b3 = *(const float4*)(Bptr + k0 + 28);
      }
#pragma unroll
      for (int kk = 0; kk < 16; ++kk) {
        float4 av0 = *(const float4*)&As[buf][kk][ty * 8];
        float4 av1 = *(const float4*)&As[buf][kk][ty * 8 + 4];
        float4 bv0 = *(const float4*)&Bs[buf][kk][tx * 4];
        float4 bv1 = *(const float4*)&Bs[buf][kk][tx * 4 + 128];
        float a[8] = {av0.x, av0.y, av0.z, av0.w, av1.x, av1.y, av1.z, av1.w};
        float b[8] = {bv0.x, bv0.y, bv0.z, bv0.w, bv1.x, bv1.y, bv1.z, bv1.w};
#pragma unroll
        for (int i = 0; i < 8; ++i)
#pragma unroll
          for (int j = 0; j < 8; ++j) acc[i][j] = fmaf(a[i], b[j], acc[i][j]);
      }
      buf ^= 1;
    }
#pragma unroll
    for (int j4 = 0; j4 < 2; ++j4) {
      int nbq = cbase + n0 + j4 * 128 + tx * 4;
      float4 ic = *(const float4*)&invc[nbq];
      float4 cq = *(const float4*)&cnsq[nbq];
      float icv[4] = {ic.x, ic.y, ic.z, ic.w};
      float cqv[4] = {cq.x, cq.y, cq.z, cq.w};
#pragma unroll
      for (int i = 0; i < 8; ++i) {
        float ir2 = 2.0f * invr_s[ty * 8 + i];
#pragma unroll
        for (int jj = 0; jj < 4; ++jj) {
          float sc = acc[i][j4 * 4 + jj] * ir2 * icv[jj] - cqv[jj];
          if (sc > best[i]) { best[i] = sc; bidx[i] = nbq + jj; }
        }
      }
    }
  }
  __syncthreads();
#pragma unroll
  for (int i = 0; i < 8; ++i) {
    red_s[ty * 8 + i][tx] = best[i];
    red_i[ty * 8 + i][tx] = bidx[i];
  }
  __syncthreads();
  if (tid < 64) {
    float bs = red_s[tid][0];
    int bi = red_i[tid][0];
#pragma unroll
    for (int t = 1; t < 32; ++t) {
      float s = red_s[tid][t];
      int ii = red_i[tid][t];
      if (s > bs || (s == bs && ii < bi)) { bs = s; bi = ii; }
    }
    cand_s[(size_t)(m0 + tid) * 2 + blockIdx.y] = bs;
    cand_i[(size_t)(m0 + tid) * 2 + blockIdx.y] = bi;
  }
}

__global__ __launch_bounds__(256) void combine_kernel(
    const float* __restrict__ cand_s, const int* __restrict__ cand_i,
    int* __restrict__ out) {
  int r = blockIdx.x * 256 + threadIdx.x;
  float s0 = cand_s[r * 2], s1 = cand_s[r * 2 + 1];
  int i0 = cand_i[r * 2], i1 = cand_i[r * 2 + 1];
  out[r] = (s1 > s0 || (s1 == s0 && i1 < i0)) ? i1 : i0;
}

// ---------------------------------------------------------------- launch
extern "C" void kernel_launch(void* const* d_in, const int* in_sizes, int n_in,
                              void* d_out, int out_size, void* d_ws, size_t ws_size,
                              hipStream_t stream) {
  const float* x  = (const float*)d_in[0];
  const float* rp = (const float*)d_in[1];
  const float* cb = (const float*)d_in[2];
  int* out = (int*)d_out;

  char* w = (char*)d_ws;
  float* proj = (float*)w;        w += (size_t)M_ROWS * E_DIM * 4;   // 32 MB
  signed char* Ahq = (signed char*)w; w += (size_t)M_ROWS * E_DIM;   // 8 MB
  signed char* Alq = (signed char*)w; w += (size_t)M_ROWS * E_DIM;   // 8 MB
  signed char* Bhq = (signed char*)w; w += (size_t)K_CB * E_DIM;     // 2 MB
  signed char* Blq = (signed char*)w; w += (size_t)K_CB * E_DIM;     // 2 MB
  float* invr = (float*)w;        w += M_ROWS * 4;
  float* invc = (float*)w;        w += K_CB * 4;
  float* cnsq = (float*)w;        w += K_CB * 4;
  float* sB   = (float*)w;        w += K_CB * 4;
  float* candb  = (float*)w;      w += (size_t)M_ROWS * 32 * 4;      // 2 MB
  float* cands2 = (float*)w;      w += (size_t)M_ROWS * 32 * 4;      // 2 MB
  int*   candi  = (int*)w;        w += (size_t)M_ROWS * 32 * 4;      // 2 MB
  float* bqv  = (float*)w;        w += M_ROWS * 4;
  int*   fixlist  = (int*)w;      w += M_ROWS * 4;
  int*   fixcount = (int*)w;      w += 64;
  size_t need = (size_t)(w - (char*)d_ws);
  short* Ph = (short*)candb;      // overlay: dead until mfma_argmax writes
  short* Pl = (short*)cands2;

  if (ws_size >= need) {
    cbnorm_split_kernel<<<K_CB / 4, 256, 0, stream>>>(cb, invc, cnsq, sB, Bhq,
                                                      Blq, fixcount);
    psplit_kernel<<<64, 256, 0, stream>>>(rp, Ph, Pl);
    gemm1_mfma_kernel<<<dim3(E_DIM / 128, M_ROWS / 128), 256, 0, stream>>>(
        x, Ph, Pl, proj, Ahq, Alq);
    row_norm_kernel<<<M_ROWS / 4, 256, 0, stream>>>(proj, invr, nullptr, nullptr);
    mfma_argmax_kernel<<<(M_ROWS / 128) * (K_CB / 128), 256, 0, stream>>>(
        Ahq, Alq, Bhq, Blq, invr, invc, cnsq, sB, candb, cands2, candi);
    combine2_kernel<<<M_ROWS / 256, 256, 0, stream>>>(
        candb, cands2, candi, out, bqv, fixlist, fixcount);
    fix_exact_kernel<<<256, 256, 0, stream>>>(
        proj, cb, invr, invc, cnsq, candb, bqv, fixlist, fixcount, out);
  } else {
    float* ws    = (float*)d_ws;
    float* proj1 = ws;
    float* invr1 = proj1 + (size_t)M_ROWS * E_DIM;
    float* invc1 = invr1 + M_ROWS;
    float* cnsq1 = invc1 + K_CB;
    float* cands = cnsq1 + K_CB;
    int*   candi1 = (int*)(cands + (size_t)M_ROWS * 2);

    row_norm_kernel<<<K_CB / 4, 256, 0, stream>>>(cb, invc1, cnsq1, nullptr);
    gemm1_kernel<<<dim3(E_DIM / 128, M_ROWS / 128), 256, 0, stream>>>(x, rp, proj1);
    row_norm_kernel<<<M_ROWS / 4, 256, 0, stream>>>(proj1, invr1, nullptr, nullptr);
    argmax_kernel<<<dim3(M_ROWS / 64, 2), 256, 0, stream>>>(proj1, cb, invr1,
                                                            invc1, cnsq1, cands, candi1);
    combine_kernel<<<M_ROWS / 256, 256, 0, stream>>>(cands, candi1, out);
  }
}

// Round 9
// 411.603 us; speedup vs baseline: 1.1277x; 1.0556x over previous
//
#include <hip/hip_runtime.h>
#include <hip/hip_bf16.h>

// Problem: RandomProjectionQuantizer  B=4 N=4096 D=1024 E=512 K=4096
// M = B*N = 16384 rows.
// proj = X @ P (fp32), scores = 2*invr_m*invc_k*(cb_k . proj_m) - cnsq_k,
// nearest = argmax_k score (ties -> min k).
// Round 20: shrink the "rest" (argmax frozen at r19's 168us).
// Ledger: best total was r12 419.9 (argmax 209 + rest 211); i8 era rest is
// ~265 - the +55us tracks TAU 1e-4 -> 4e-4 (fixlist ~ P(gap<TAU) ~ 10% of
// rows = ~2000, 4x my r15 assumption; fix volume ~ TAU).  Error budget
// (validated by 6x absmax=0 at TAU=14-sigma): sigma ~ 2.8e-5 -> TAU=2e-4
// is 7-sigma, still safe, halves fix volume.
// gemm1: nb-fast grid round-robins the 4 blocks sharing an X-tile across 4
// XCDs -> X pulled ~4x through L3 (~268MB).  XCD-chunked swizzle (T1) puts
// all 4 nb-blocks of an mb on one XCD -> X-tile L2-shared.

#define M_ROWS 16384
#define D_DIM  1024
#define E_DIM  512
#define K_CB   4096
#define EPS_N  1e-12f
#define TAU_FIX 2e-4f
#define NEG_INF (-3.4e38f)
#define S_A_NUM 12.0f   // fixed A-scale: proj elem std ~1.155, 12.0 ~ 10.4 sigma

typedef short bf16x8 __attribute__((ext_vector_type(8)));
typedef _Float16 f16x8 __attribute__((ext_vector_type(8)));
typedef short s16x4 __attribute__((ext_vector_type(4)));
typedef float f32x4  __attribute__((ext_vector_type(4)));
typedef int   i32x4  __attribute__((ext_vector_type(4)));

// ---------------------------------------------------------------- helpers
__device__ __forceinline__ unsigned short f32_to_bf16_rtne(float x) {
  unsigned u = __float_as_uint(x);
  unsigned r = u + 0x7FFFu + ((u >> 16) & 1u);
  return (unsigned short)(r >> 16);
}
__device__ __forceinline__ float bf16_bits_to_f32(unsigned short h) {
  return __uint_as_float(((unsigned)h) << 16);
}
__device__ __forceinline__ void split_f16(float x, short& hs, short& ls) {
  _Float16 h = (_Float16)x;
  float hf = (float)h;
  _Float16 l = (_Float16)(x - hf);
  hs = __builtin_bit_cast(short, h);
  ls = __builtin_bit_cast(short, l);
}
__device__ __forceinline__ void g2l16(const void* g, void* l) {
  __builtin_amdgcn_global_load_lds(
      (const __attribute__((address_space(1))) unsigned*)g,
      (__attribute__((address_space(3))) unsigned*)l, 16, 0, 0);
}
__device__ __forceinline__ i32x4 mfma_i8(i32x4 a, i32x4 b, i32x4 c) {
  return __builtin_amdgcn_mfma_i32_16x16x64_i8(a, b, c, 0, 0, 0);
}
// quantize x (already scaled to q-units, |q|<=16256) into h,l int8
__device__ __forceinline__ void split_i8(float qv, signed char& h,
                                         signed char& l) {
  float hf = rintf(qv * (1.0f / 128.0f));
  float lf = qv - 128.0f * hf;
  h = (signed char)(int)hf;
  l = (signed char)(int)lf;
}

// ---------------------------------------------------------------- row norms
__global__ __launch_bounds__(256) void row_norm_kernel(
    const float* __restrict__ src, float* __restrict__ inv_out,
    float* __restrict__ sq_out, int* __restrict__ zero_me) {
  if (zero_me && blockIdx.x == 0 && threadIdx.x == 0) *zero_me = 0;
  int row  = blockIdx.x * 4 + (threadIdx.x >> 6);
  int lane = threadIdx.x & 63;
  const float4* p = (const float4*)(src + (size_t)row * E_DIM);
  float4 v0 = p[lane];
  float4 v1 = p[lane + 64];
  float s = v0.x * v0.x + v0.y * v0.y + v0.z * v0.z + v0.w * v0.w +
            v1.x * v1.x + v1.y * v1.y + v1.z * v1.z + v1.w * v1.w;
#pragma unroll
  for (int m = 32; m; m >>= 1) s += __shfl_xor(s, m, 64);
  float d = fmaxf(sqrtf(s), EPS_N);
  if (sq_out) {
    float q0 = v0.x / d, q1 = v0.y / d, q2 = v0.z / d, q3 = v0.w / d;
    float q4 = v1.x / d, q5 = v1.y / d, q6 = v1.z / d, q7 = v1.w / d;
    float q = q0 * q0 + q1 * q1 + q2 * q2 + q3 * q3 +
              q4 * q4 + q5 * q5 + q6 * q6 + q7 * q7;
#pragma unroll
    for (int m = 32; m; m >>= 1) q += __shfl_xor(q, m, 64);
    if (lane == 0) sq_out[row] = q;
  }
  if (lane == 0) inv_out[row] = 1.0f / d;
}

// ---------------------------------------------------------------- cb norm+split
// Per codebook row: invc, cnsq, per-row i8 scale sB, and i8 h/l fragments in
// mfma_i32_16x16x64_i8 B-layout: byte idx =
// ((nb*8 + kc8)*512 + q*128 + row128)*16 + j16, kc8=k>>6, q=(k&63)>>4, j16=k&15.
__global__ __launch_bounds__(256) void cbnorm_split_kernel(
    const float* __restrict__ cb, float* __restrict__ invc,
    float* __restrict__ cnsq, float* __restrict__ sB,
    signed char* __restrict__ Bhq, signed char* __restrict__ Blq,
    int* __restrict__ zero_me) {
  if (zero_me && blockIdx.x == 0 && threadIdx.x == 0) *zero_me = 0;
  int r    = blockIdx.x * 4 + (threadIdx.x >> 6);
  int lane = threadIdx.x & 63;
  const float* src = cb + (size_t)r * E_DIM + lane * 8;
  float4 v0 = *(const float4*)src;
  float4 v1 = *(const float4*)(src + 4);
  float v[8] = {v0.x, v0.y, v0.z, v0.w, v1.x, v1.y, v1.z, v1.w};
  float s = 0.f;
#pragma unroll
  for (int j = 0; j < 8; ++j) s = fmaf(v[j], v[j], s);
#pragma unroll
  for (int m = 32; m; m >>= 1) s += __shfl_xor(s, m, 64);
  float d = fmaxf(sqrtf(s), EPS_N);
  float q = 0.f;
#pragma unroll
  for (int j = 0; j < 8; ++j) { float t = v[j] / d; q = fmaf(t, t, q); }
#pragma unroll
  for (int m = 32; m; m >>= 1) q += __shfl_xor(q, m, 64);
  float am = 0.f;
#pragma unroll
  for (int j = 0; j < 8; ++j) am = fmaxf(am, fabsf(v[j]));
#pragma unroll
  for (int m = 32; m; m >>= 1) am = fmaxf(am, __shfl_xor(am, m, 64));
  float inv_sb = (am > 0.f) ? (16256.0f / am) : 0.0f;
  if (lane == 0) {
    cnsq[r] = q;
    invc[r] = 1.0f / d;
    sB[r] = (am > 0.f) ? (am / 16256.0f) : 0.0f;
  }
  union { signed char c8[8]; uint2 u; } Hq, Lq;
#pragma unroll
  for (int j = 0; j < 8; ++j) {
    float qv = rintf(v[j] * inv_sb);  // |qv| <= 16256 by construction
    split_i8(qv, Hq.c8[j], Lq.c8[j]);
  }
  int nb = r >> 7, row = r & 127;
  int kc8 = lane >> 3, qq = (lane & 7) >> 1, jh = lane & 1;
  size_t idx = (((size_t)(nb * 8 + kc8) * 512) + qq * 128 + row) * 16 + jh * 8;
  *(uint2*)(Bhq + idx) = Hq.u;
  *(uint2*)(Blq + idx) = Lq.u;
}

// ---------------------------------------------------------------- P split
__global__ __launch_bounds__(256) void psplit_kernel(
    const float* __restrict__ P, short* __restrict__ Ph,
    short* __restrict__ Pl) {
  int tid = threadIdx.x;
#pragma unroll
  for (int i = 0; i < 4; ++i) {
    int g = blockIdx.x * 1024 + i * 256 + tid;  // 0..65535
    int k8 = g >> 9, col = g & 511;
    int nb = col >> 7, c = col & 127;
    int kc = k8 >> 2, q = k8 & 3;
    union { short s8[8]; float4 f; } H, L;
#pragma unroll
    for (int j = 0; j < 8; ++j) {
      float v = P[(size_t)(k8 * 8 + j) * 512 + col] * 4096.0f;
      split_f16(v, H.s8[j], L.s8[j]);
    }
    size_t dst = (((size_t)(nb * 32 + kc) * 4 + q) * 128 + c) * 8;
    *(float4*)(Ph + dst) = H.f;
    *(float4*)(Pl + dst) = L.f;
  }
}

// ---------------------------------------------------------------- GEMM1 (MFMA)
// proj = X @ P via fp16-split MFMA (hh+hl+lh), scale 4096^2 backed out.
// Epilogue writes proj fp32 + i8 h/l A-fragments (fixed scale 12/16256) in
// mfma_i32_16x16x64_i8 A-layout.
// Grid is 1D (512) with XCD-chunked swizzle: all 4 nb-blocks of an mb land
// on the same XCD so the 512KB X-tile is L2-shared (was fetched ~4x via L3).
__global__ __launch_bounds__(256, 2) void gemm1_mfma_kernel(
    const float* __restrict__ X, const short* __restrict__ Ph,
    const short* __restrict__ Pl, float* __restrict__ proj,
    signed char* __restrict__ Ahq, signed char* __restrict__ Alq) {
  __shared__ short lds_ah[4096];
  __shared__ short lds_al[4096];
  __shared__ short lds_bh[4096];
  __shared__ short lds_bl[4096];
  int tid = threadIdx.x;
  int wid = tid >> 6, lane = tid & 63;
  // XCD-chunked swizzle: xcd = lin&7 gets contiguous ids [xcd*64,(xcd+1)*64)
  // -> mb range [xcd*16, xcd*16+16), nb fast within mb.
  int lin = blockIdx.x;
  int g = (lin & 7) * 64 + (lin >> 3);
  int mb = g >> 2, nb = g & 3;
  int m0 = mb * 128, n0 = nb * 128;
  int wm = wid >> 1, wn = wid & 1;
  int q4 = lane >> 4, c0 = lane & 15;

  f32x4 zero = {0.f, 0.f, 0.f, 0.f};
  f32x4 acc[4][4];
#pragma unroll
  for (int i = 0; i < 4; ++i)
#pragma unroll
    for (int j = 0; j < 4; ++j) acc[i][j] = zero;

  for (int kc = 0; kc < 32; ++kc) {
    const char* gb = (const char*)Ph + ((size_t)(nb * 32 + kc)) * 8192;
    const char* gl = (const char*)Pl + ((size_t)(nb * 32 + kc)) * 8192;
#pragma unroll
    for (int p = 0; p < 4; ++p) {
      int s = wid * 4 + p;
      int t = s >> 3;
      int off = (s & 7) * 1024;
      const char* src = (t == 0 ? gb : gl) + off + lane * 16;
      char* dst = (char*)(t == 0 ? lds_bh : lds_bl) + off;
      g2l16(src, dst);
    }
#pragma unroll
    for (int i = 0; i < 4; ++i) {
      int e = i * 1024 + tid * 4;
      int row = e >> 5, k4 = e & 31;
      int q = k4 >> 3, j0 = k4 & 7;
      float4 xv = *(const float4*)(X + (size_t)(m0 + row) * D_DIM + kc * 32 + k4);
      float v[4] = {xv.x * 4096.f, xv.y * 4096.f, xv.z * 4096.f, xv.w * 4096.f};
      s16x4 H, L;
#pragma unroll
      for (int j = 0; j < 4; ++j) {
        short hs, ls;
        split_f16(v[j], hs, ls);
        H[j] = hs; L[j] = ls;
      }
      int o = (q * 128 + row) * 8 + j0;
      *(s16x4*)&lds_ah[o] = H;
      *(s16x4*)&lds_al[o] = L;
    }
    __syncthreads();

    f16x8 bh[4], bl[4];
#pragma unroll
    for (int ni = 0; ni < 4; ++ni) {
      int boff = (q4 * 128 + wn * 64 + ni * 16 + c0) * 8;
      bh[ni] = *(const f16x8*)&lds_bh[boff];
      bl[ni] = *(const f16x8*)&lds_bl[boff];
    }
#pragma unroll
    for (int mi = 0; mi < 4; ++mi) {
      int aoff = (q4 * 128 + wm * 64 + mi * 16 + c0) * 8;
      f16x8 ah = *(const f16x8*)&lds_ah[aoff];
      f16x8 al = *(const f16x8*)&lds_al[aoff];
#pragma unroll
      for (int ni = 0; ni < 4; ++ni) {
        acc[mi][ni] = __builtin_amdgcn_mfma_f32_16x16x32_f16(
            ah, bh[ni], acc[mi][ni], 0, 0, 0);
        acc[mi][ni] = __builtin_amdgcn_mfma_f32_16x16x32_f16(
            ah, bl[ni], acc[mi][ni], 0, 0, 0);
        acc[mi][ni] = __builtin_amdgcn_mfma_f32_16x16x32_f16(
            al, bh[ni], acc[mi][ni], 0, 0, 0);
      }
    }
    __syncthreads();
  }

  const float inv_s = 1.0f / 16777216.0f;
  const float QA = 16256.0f / S_A_NUM;
#pragma unroll
  for (int ni = 0; ni < 4; ++ni) {
    int gcol = n0 + wn * 64 + ni * 16 + c0;
    int kc8 = gcol >> 6, qe = (gcol & 63) >> 4, je = gcol & 15;
    size_t ibase = (((size_t)(mb * 8 + kc8) * 512) + qe * 128) * 16 + je;
#pragma unroll
    for (int mi = 0; mi < 4; ++mi) {
#pragma unroll
      for (int r = 0; r < 4; ++r) {
        int rl = wm * 64 + mi * 16 + q4 * 4 + r;
        float val = acc[mi][ni][r] * inv_s;
        proj[(size_t)(m0 + rl) * E_DIM + gcol] = val;
        float qv = rintf(fminf(fmaxf(val * QA, -16256.f), 16256.f));
        signed char hq, lq;
        split_i8(qv, hq, lq);
        size_t idx = ibase + (size_t)rl * 16;
        Ahq[idx] = hq;
        Alq[idx] = lq;
      }
    }
  }
}

// ---------------------------------------------------------------- MFMA argmax
// INT8 register-pipelined LDS-free K-loop (r14-exact structure, 168us).
// Grid 4096 linear, swizzled into 4mb x 8nb tiles (mb 0..127, nb 0..31).
// Block tile 128x128, 4 waves 2x2, wave tile 64x64.
// Per K-chunk (K=64): 3 passes of 16 mfma_i32_16x16x64_i8:
//   accH += h_a.h_b ; accM += h_a.l_b ; accM += l_a.h_b   (l.l dropped)
// B-fragments double-buffered across chunks; A-fragments reloaded mid-chunk
// right after their last use.  No LDS, no barriers in the K-loop.
// Cand output layout TRANSPOSED [nb][row] (r19: write-amp 49MB -> 6MB).
__device__ __forceinline__ void ld_bset(i32x4 (&bh)[4], i32x4 (&bl)[4],
                                        const char* pBh, const char* pBl,
                                        int kc) {
#pragma unroll
  for (int ni = 0; ni < 4; ++ni) {
    bh[ni] = *(const i32x4*)(pBh + kc * 8192 + ni * 256);
    bl[ni] = *(const i32x4*)(pBl + kc * 8192 + ni * 256);
  }
}
__device__ __forceinline__ void ld_ah4(i32x4 (&ah)[4], const char* pAh, int kc) {
#pragma unroll
  for (int mi = 0; mi < 4; ++mi)
    ah[mi] = *(const i32x4*)(pAh + kc * 8192 + mi * 256);
}
__device__ __forceinline__ void ld_al4(i32x4 (&al)[4], const char* pAl, int kc) {
#pragma unroll
  for (int mi = 0; mi < 4; ++mi)
    al[mi] = *(const i32x4*)(pAl + kc * 8192 + mi * 256);
}

__device__ __forceinline__ void passes_i8(
    i32x4 (&accH)[4][4], i32x4 (&accM)[4][4], i32x4 (&ah)[4], i32x4 (&al)[4],
    const i32x4 (&bh)[4], const i32x4 (&bl)[4], const char* pAh,
    const char* pAl, int nkc, bool doA) {
#pragma unroll
  for (int mi = 0; mi < 4; ++mi)
#pragma unroll
    for (int ni = 0; ni < 4; ++ni)
      accH[mi][ni] = mfma_i8(ah[mi], bh[ni], accH[mi][ni]);
#pragma unroll
  for (int mi = 0; mi < 4; ++mi)
#pragma unroll
    for (int ni = 0; ni < 4; ++ni)
      accM[mi][ni] = mfma_i8(ah[mi], bl[ni], accM[mi][ni]);
  if (doA) ld_ah4(ah, pAh, nkc);   // ah dead after pass 2
#pragma unroll
  for (int mi = 0; mi < 4; ++mi)
#pragma unroll
    for (int ni = 0; ni < 4; ++ni)
      accM[mi][ni] = mfma_i8(al[mi], bh[ni], accM[mi][ni]);
  if (doA) ld_al4(al, pAl, nkc);   // al dead after pass 3
}

__global__ __launch_bounds__(256, 2) void mfma_argmax_kernel(
    const signed char* __restrict__ Ahq, const signed char* __restrict__ Alq,
    const signed char* __restrict__ Bhq, const signed char* __restrict__ Blq,
    const float* __restrict__ invr, const float* __restrict__ invc,
    const float* __restrict__ cnsq, const float* __restrict__ sB,
    float* __restrict__ candb, float* __restrict__ cands2,
    int* __restrict__ candi) {
  __shared__ float msb[256];
  __shared__ float mss[256];
  __shared__ int   msi[256];
  int tid = threadIdx.x;
  int wid = tid >> 6, lane = tid & 63;
  // swizzle: 32-block tiles of 4 mb x 8 nb for per-XCD L2 locality
  int lin = blockIdx.x;
  int tile = lin >> 5, wi = lin & 31;
  int tnb = tile & 3, tmb = tile >> 2;   // tnb 0..3, tmb 0..31
  int nb = tnb * 8 + (wi & 7);           // 0..31
  int mb = tmb * 4 + (wi >> 3);          // 0..127

  int wm = wid >> 1, wn = wid & 1;
  int q = lane >> 4, c0 = lane & 15;

  // per-lane fragment base pointers (byte units; 65536 B per 128-row panel)
  const char* pAh = (const char*)Ahq + (size_t)mb * 65536 +
                    (q * 128 + wm * 64 + c0) * 16;
  const char* pAl = (const char*)Alq + (size_t)mb * 65536 +
                    (q * 128 + wm * 64 + c0) * 16;
  const char* pBh = (const char*)Bhq + (size_t)nb * 65536 +
                    (q * 128 + wn * 64 + c0) * 16;
  const char* pBl = (const char*)Blq + (size_t)nb * 65536 +
                    (q * 128 + wn * 64 + c0) * 16;

  i32x4 zero = {0, 0, 0, 0};
  i32x4 accH[4][4], accM[4][4];
#pragma unroll
  for (int i = 0; i < 4; ++i)
#pragma unroll
    for (int j = 0; j < 4; ++j) { accH[i][j] = zero; accM[i][j] = zero; }

  i32x4 ah[4], al[4], bh0[4], bl0[4], bh1[4], bl1[4];
  ld_bset(bh0, bl0, pBh, pBl, 0);
  ld_ah4(ah, pAh, 0);
  ld_al4(al, pAl, 0);
  for (int t = 0; t < 6; t += 2) {
    ld_bset(bh1, bl1, pBh, pBl, t + 1);
    passes_i8(accH, accM, ah, al, bh0, bl0, pAh, pAl, t + 1, true);
    ld_bset(bh0, bl0, pBh, pBl, t + 2);
    passes_i8(accH, accM, ah, al, bh1, bl1, pAh, pAl, t + 2, true);
  }
  ld_bset(bh1, bl1, pBh, pBl, 7);
  passes_i8(accH, accM, ah, al, bh0, bl0, pAh, pAl, 7, true);   // chunk 6
  passes_i8(accH, accM, ah, al, bh1, bl1, pAh, pAl, 0, false);  // chunk 7

  // epilogue: score = (16384*accH + 128*accM) * (2*S_A*invr) * (sB*invc) - cnsq
  float icv[4], cqv[4];
#pragma unroll
  for (int ni = 0; ni < 4; ++ni) {
    int n = nb * 128 + wn * 64 + ni * 16 + c0;
    icv[ni] = invc[n] * sB[n];
    cqv[ni] = cnsq[n];
  }
  const float SA = S_A_NUM / 16256.0f;
#pragma unroll
  for (int mi = 0; mi < 4; ++mi) {
    float4 ir4 = *(const float4*)&invr[mb * 128 + wm * 64 + mi * 16 + q * 4];
    float irv[4] = {ir4.x, ir4.y, ir4.z, ir4.w};
#pragma unroll
    for (int r = 0; r < 4; ++r) {
      float tir = 2.0f * SA * irv[r];
      float b = NEG_INF, s = NEG_INF;
      int bi = 2147483647;
#pragma unroll
      for (int ni = 0; ni < 4; ++ni) {
        float hsum = 16384.0f * (float)accH[mi][ni][r] +
                     128.0f * (float)accM[mi][ni][r];
        float v = hsum * (tir * icv[ni]) - cqv[ni];
        int n = nb * 128 + wn * 64 + ni * 16 + c0;
        if (v > b) { s = b; b = v; bi = n; } else { s = fmaxf(s, v); }
      }
#pragma unroll
      for (int off = 1; off < 16; off <<= 1) {
        float ob = __shfl_xor(b, off, 64);
        float os = __shfl_xor(s, off, 64);
        int   oi = __shfl_xor(bi, off, 64);
        if (ob > b || (ob == b && oi < bi)) {
          s = fmaxf(b, os); b = ob; bi = oi;
        } else {
          s = fmaxf(s, ob);
        }
      }
      if (c0 == 0) {
        int rl = wm * 64 + mi * 16 + q * 4 + r;  // 0..127 within block
        msb[wn * 128 + rl] = b;
        mss[wn * 128 + rl] = s;
        msi[wn * 128 + rl] = bi;
      }
    }
  }
  __syncthreads();
  if (tid < 128) {
    float b0 = msb[tid],       s0 = mss[tid];
    float b1 = msb[128 + tid], s1 = mss[128 + tid];
    int   i0 = msi[tid],       i1 = msi[128 + tid];
    float B, S; int I;
    if (b1 > b0 || (b1 == b0 && i1 < i0)) {
      B = b1; S = fmaxf(s1, b0); I = i1;
    } else {
      B = b0; S = fmaxf(s0, b1); I = i0;
    }
    // TRANSPOSED cand layout: [nb][row] -> 512B contiguous runs
    size_t o = (size_t)nb * M_ROWS + mb * 128 + tid;
    candb[o] = B; cands2[o] = S; candi[o] = I;
  }
}

// ---------------------------------------------------------------- combine
// Global top-2 merge across the 32 nb-blocks; writes out, the quantized
// global best (bqv, used by the fix filter), and the fixlist trigger.
// Cand arrays are [nb][row]: per nb-iteration the 256 threads read 1KB
// coalesced runs.
__global__ __launch_bounds__(256) void combine2_kernel(
    const float* __restrict__ candb, const float* __restrict__ cands2,
    const int* __restrict__ candi, int* __restrict__ out,
    float* __restrict__ bqv, int* __restrict__ fixlist,
    int* __restrict__ fixcount) {
  int r = blockIdx.x * 256 + threadIdx.x;
  float b = NEG_INF, s = NEG_INF;
  int bi = 2147483647;
#pragma unroll 4
  for (int j = 0; j < 32; ++j) {
    size_t o = (size_t)j * M_ROWS + r;
    float cb_ = candb[o], cs_ = cands2[o];
    int ci_ = candi[o];
    if (cb_ > b || (cb_ == b && ci_ < bi)) {
      s = fmaxf(b, cs_); b = cb_; bi = ci_;
    } else {
      s = fmaxf(s, cb_);
    }
  }
  out[r] = bi;
  bqv[r] = b;
  if (b - s < TAU_FIX) {
    int p = atomicAdd(fixcount, 1);
    if (p < M_ROWS) fixlist[p] = r;
  }
}

// ---------------------------------------------------------------- fixup
// Block-filtered exact rescan: one wave per fix row.  The true argmax's
// quantized score is >= global_best - 7*sigma (sigma ~2.8e-5 << TAU), so
// its 128-code block must have candb >= bqv - TAU.  Rescan only those
// blocks (typically 1-2 of 32) with exact fp32 dots; ascending k + strict
// '>' preserves the min-k tie rule.  Direct out[] write (one wave owns the
// row; no race).
__global__ __launch_bounds__(256) void fix_exact_kernel(
    const float* __restrict__ proj, const float* __restrict__ CB,
    const float* __restrict__ invr, const float* __restrict__ invc,
    const float* __restrict__ cnsq, const float* __restrict__ candb,
    const float* __restrict__ bqv, const int* __restrict__ fixlist,
    const int* __restrict__ fixcount, int* __restrict__ out) {
  int n = *fixcount;
  if (n > M_ROWS) n = M_ROWS;
  int nwaves = gridDim.x * 4;
  int gw = blockIdx.x * 4 + (threadIdx.x >> 6);
  int lane = threadIdx.x & 63;
  for (int it = gw; it < n; it += nwaves) {
    int r = fixlist[it];
    const float* pr = proj + (size_t)r * E_DIM + lane * 8;
    float4 p0 = *(const float4*)pr;
    float4 p1 = *(const float4*)(pr + 4);
    float tir = 2.0f * invr[r];
    float thresh = bqv[r] - TAU_FIX;
    float best = NEG_INF;
    int bi = 2147483647;
    for (int nb = 0; nb < 32; ++nb) {
      if (candb[(size_t)nb * M_ROWS + r] < thresh) continue;
      int k0 = nb * 128;
#pragma unroll 2
      for (int k = k0; k < k0 + 128; ++k) {
        const float* cr = CB + (size_t)k * E_DIM + lane * 8;
        float4 c0 = *(const float4*)cr;
        float4 c1 = *(const float4*)(cr + 4);
        float t = 0.f;
        t = fmaf(c0.x, p0.x, t); t = fmaf(c0.y, p0.y, t);
        t = fmaf(c0.z, p0.z, t); t = fmaf(c0.w, p0.w, t);
        t = fmaf(c1.x, p1.x, t); t = fmaf(c1.y, p1.y, t);
        t = fmaf(c1.z, p1.z, t); t = fmaf(c1.w, p1.w, t);
#pragma unroll
        for (int m = 1; m < 64; m <<= 1) t += __shfl_xor(t, m, 64);
        float sc = tir * invc[k] * t - cnsq[k];
        if (sc > best) { best = sc; bi = k; }
      }
    }
    if (lane == 0) out[r] = bi;
  }
}

// ================================================================ fallback
__global__ __launch_bounds__(256, 2) void gemm1_kernel(
    const float* __restrict__ A, const float* __restrict__ Bm,
    float* __restrict__ C) {
  __shared__ float As[2][16][132];
  __shared__ float Bs[2][16][128];
  int tid = threadIdx.x;
  int tx = tid & 15, ty = tid >> 4;
  int n0 = blockIdx.x * 128;
  int m0 = blockIdx.y * 128;

  int arow = tid >> 2;
  int akq  = (tid & 3) * 4;
  int bk   = tid >> 5;
  int bcol = (tid & 31) * 4;

  const float* Aptr  = A + (size_t)(m0 + arow) * D_DIM + akq;
  const float* Aptr2 = Aptr + (size_t)64 * D_DIM;
  const float* Bptr  = Bm + (size_t)bk * E_DIM + n0 + bcol;
  const float* Bptr2 = Bptr + (size_t)8 * E_DIM;

  float acc[8][8] = {};
  float4 a0 = *(const float4*)(Aptr);
  float4 a1 = *(const float4*)(Aptr2);
  float4 b0 = *(const float4*)(Bptr);
  float4 b1 = *(const float4*)(Bptr2);

  int buf = 0;
  for (int k0 = 0; k0 < D_DIM; k0 += 16) {
    As[buf][akq + 0][arow] = a0.x;
    As[buf][akq + 1][arow] = a0.y;
    As[buf][akq + 2][arow] = a0.z;
    As[buf][akq + 3][arow] = a0.w;
    As[buf][akq + 0][arow + 64] = a1.x;
    As[buf][akq + 1][arow + 64] = a1.y;
    As[buf][akq + 2][arow + 64] = a1.z;
    As[buf][akq + 3][arow + 64] = a1.w;
    *(float4*)&Bs[buf][bk][bcol]     = b0;
    *(float4*)&Bs[buf][bk + 8][bcol] = b1;
    __syncthreads();
    if (k0 + 16 < D_DIM) {
      a0 = *(const float4*)(Aptr + k0 + 16);
      a1 = *(const float4*)(Aptr2 + k0 + 16);
      b0 = *(const float4*)(Bptr + (size_t)(k0 + 16) * E_DIM);
      b1 = *(const float4*)(Bptr2 + (size_t)(k0 + 16) * E_DIM);
    }
#pragma unroll
    for (int kk = 0; kk < 16; ++kk) {
      float4 av0 = *(const float4*)&As[buf][kk][ty * 8];
      float4 av1 = *(const float4*)&As[buf][kk][ty * 8 + 4];
      float4 bv0 = *(const float4*)&Bs[buf][kk][tx * 4];
      float4 bv1 = *(const float4*)&Bs[buf][kk][tx * 4 + 64];
      float a[8] = {av0.x, av0.y, av0.z, av0.w, av1.x, av1.y, av1.z, av1.w};
      float b[8] = {bv0.x, bv0.y, bv0.z, bv0.w, bv1.x, bv1.y, bv1.z, bv1.w};
#pragma unroll
      for (int i = 0; i < 8; ++i)
#pragma unroll
        for (int j = 0; j < 8; ++j) acc[i][j] = fmaf(a[i], b[j], acc[i][j]);
    }
    buf ^= 1;
  }
#pragma unroll
  for (int i = 0; i < 8; ++i) {
    float* crow = C + (size_t)(m0 + ty * 8 + i) * E_DIM + n0;
    *(float4*)(crow + tx * 4)      = make_float4(acc[i][0], acc[i][1], acc[i][2], acc[i][3]);
    *(float4*)(crow + tx * 4 + 64) = make_float4(acc[i][4], acc[i][5], acc[i][6], acc[i][7]);
  }
}

__global__ __launch_bounds__(256, 2) void argmax_kernel(
    const float* __restrict__ P, const float* __restrict__ CB,
    const float* __restrict__ invr, const float* __restrict__ invc,
    const float* __restrict__ cnsq, float* __restrict__ cand_s,
    int* __restrict__ cand_i) {
  __shared__ float As[2][16][68];
  __shared__ float Bs[2][16][256];
  __shared__ float invr_s[64];
  __shared__ float red_s[64][33];
  __shared__ int   red_i[64][33];

  int tid = threadIdx.x;
  int tx = tid & 31, ty = tid >> 5;
  int m0 = blockIdx.x * 64;
  int cbase = blockIdx.y * 2048;
  if (tid < 64) invr_s[tid] = invr[m0 + tid];
  int arow = tid >> 2;
  int akq  = (tid & 3) * 4;
  const float* Aptr = P + (size_t)(m0 + arow) * E_DIM + akq;

  float best[8];
  int   bidx[8];
#pragma unroll
  for (int i = 0; i < 8; ++i) { best[i] = NEG_INF; bidx[i] = 0; }

  for (int n0 = 0; n0 < 2048; n0 += 256) {
    const float* Bptr = CB + (size_t)(cbase + n0 + tid) * E_DIM;
    float4 a0 = *(const float4*)(Aptr);
    float4 b0 = *(const float4*)(Bptr + 0);
    float4 b1 = *(const float4*)(Bptr + 4);
    float4 b2 = *(const float4*)(Bptr + 8);
    float4 b3 = *(const float4*)(Bptr + 12);
    float acc[8][8] = {};
    int buf = 0;
    for (int k0 = 0; k0 < E_DIM; k0 += 16) {
      As[buf][akq + 0][arow] = a0.x;
      As[buf][akq + 1][arow] = a0.y;
      As[buf][akq + 2][arow] = a0.z;
      As[buf][akq + 3][arow] = a0.w;
      Bs[buf][0][tid] = b0.x;  Bs[buf][1][tid] = b0.y;
      Bs[buf][2][tid] = b0.z;  Bs[buf][3][tid] = b0.w;
      Bs[buf][4][tid] = b1.x;  Bs[buf][5][tid] = b1.y;
      Bs[buf][6][tid] = b1.z;  Bs[buf][7][tid] = b1.w;
      Bs[buf][8][tid] = b2.x;  Bs[buf][9][tid] = b2.y;
      Bs[buf][10][tid] = b2.z; Bs[buf][11][tid] = b2.w;
      Bs[buf][12][tid] = b3.x; Bs[buf][13][tid] = b3.y;
      Bs[buf][14][tid] = b3.z; Bs[buf][15][tid] = b3.w;
      __syncthreads();
      if (k0 + 16 < E_DIM) {
        a0 = *(const float4*)(Aptr + k0 + 16);
        b0 = *(const float4*)(Bptr + k0 + 16);
        b1 = *(const float4*)(Bptr + k0 + 20);
        b2 = *(const float4*)(Bptr + k0 + 24);
        b3 = *(const float4*)(Bptr + k0 + 28);
      }
#pragma unroll
      for (int kk = 0; kk < 16; ++kk) {
        float4 av0 = *(const float4*)&As[buf][kk][ty * 8];
        float4 av1 = *(const float4*)&As[buf][kk][ty * 8 + 4];
        float4 bv0 = *(const float4*)&Bs[buf][kk][tx * 4];
        float4 bv1 = *(const float4*)&Bs[buf][kk][tx * 4 + 128];
        float a[8] = {av0.x, av0.y, av0.z, av0.w, av1.x, av1.y, av1.z, av1.w};
        float b[8] = {bv0.x, bv0.y, bv0.z, bv0.w, bv1.x, bv1.y, bv1.z, bv1.w};
#pragma unroll
        for (int i = 0; i < 8; ++i)
#pragma unroll
          for (int j = 0; j < 8; ++j) acc[i][j] = fmaf(a[i], b[j], acc[i][j]);
      }
      buf ^= 1;
    }
#pragma unroll
    for (int j4 = 0; j4 < 2; ++j4) {
      int nbq = cbase + n0 + j4 * 128 + tx * 4;
      float4 ic = *(const float4*)&invc[nbq];
      float4 cq = *(const float4*)&cnsq[nbq];
      float icv[4] = {ic.x, ic.y, ic.z, ic.w};
      float cqv[4] = {cq.x, cq.y, cq.z, cq.w};
#pragma unroll
      for (int i = 0; i < 8; ++i) {
        float ir2 = 2.0f * invr_s[ty * 8 + i];
#pragma unroll
        for (int jj = 0; jj < 4; ++jj) {
          float sc = acc[i][j4 * 4 + jj] * ir2 * icv[jj] - cqv[jj];
          if (sc > best[i]) { best[i] = sc; bidx[i] = nbq + jj; }
        }
      }
    }
  }
  __syncthreads();
#pragma unroll
  for (int i = 0; i < 8; ++i) {
    red_s[ty * 8 + i][tx] = best[i];
    red_i[ty * 8 + i][tx] = bidx[i];
  }
  __syncthreads();
  if (tid < 64) {
    float bs = red_s[tid][0];
    int bi = red_i[tid][0];
#pragma unroll
    for (int t = 1; t < 32; ++t) {
      float s = red_s[tid][t];
      int ii = red_i[tid][t];
      if (s > bs || (s == bs && ii < bi)) { bs = s; bi = ii; }
    }
    cand_s[(size_t)(m0 + tid) * 2 + blockIdx.y] = bs;
    cand_i[(size_t)(m0 + tid) * 2 + blockIdx.y] = bi;
  }
}

__global__ __launch_bounds__(256) void combine_kernel(
    const float* __restrict__ cand_s, const int* __restrict__ cand_i,
    int* __restrict__ out) {
  int r = blockIdx.x * 256 + threadIdx.x;
  float s0 = cand_s[r * 2], s1 = cand_s[r * 2 + 1];
  int i0 = cand_i[r * 2], i1 = cand_i[r * 2 + 1];
  out[r] = (s1 > s0 || (s1 == s0 && i1 < i0)) ? i1 : i0;
}

// ---------------------------------------------------------------- launch
extern "C" void kernel_launch(void* const* d_in, const int* in_sizes, int n_in,
                              void* d_out, int out_size, void* d_ws, size_t ws_size,
                              hipStream_t stream) {
  const float* x  = (const float*)d_in[0];
  const float* rp = (const float*)d_in[1];
  const float* cb = (const float*)d_in[2];
  int* out = (int*)d_out;

  char* w = (char*)d_ws;
  float* proj = (float*)w;        w += (size_t)M_ROWS * E_DIM * 4;   // 32 MB
  signed char* Ahq = (signed char*)w; w += (size_t)M_ROWS * E_DIM;   // 8 MB
  signed char* Alq = (signed char*)w; w += (size_t)M_ROWS * E_DIM;   // 8 MB
  signed char* Bhq = (signed char*)w; w += (size_t)K_CB * E_DIM;     // 2 MB
  signed char* Blq = (signed char*)w; w += (size_t)K_CB * E_DIM;     // 2 MB
  float* invr = (float*)w;        w += M_ROWS * 4;
  float* invc = (float*)w;        w += K_CB * 4;
  float* cnsq = (float*)w;        w += K_CB * 4;
  float* sB   = (float*)w;        w += K_CB * 4;
  float* candb  = (float*)w;      w += (size_t)M_ROWS * 32 * 4;      // 2 MB
  float* cands2 = (float*)w;      w += (size_t)M_ROWS * 32 * 4;      // 2 MB
  int*   candi  = (int*)w;        w += (size_t)M_ROWS * 32 * 4;      // 2 MB
  float* bqv  = (float*)w;        w += M_ROWS * 4;
  int*   fixlist  = (int*)w;      w += M_ROWS * 4;
  int*   fixcount = (int*)w;      w += 64;
  size_t need = (size_t)(w - (char*)d_ws);
  short* Ph = (short*)candb;      // overlay: dead until mfma_argmax writes
  short* Pl = (short*)cands2;

  if (ws_size >= need) {
    cbnorm_split_kernel<<<K_CB / 4, 256, 0, stream>>>(cb, invc, cnsq, sB, Bhq,
                                                      Blq, fixcount);
    psplit_kernel<<<64, 256, 0, stream>>>(rp, Ph, Pl);
    gemm1_mfma_kernel<<<(E_DIM / 128) * (M_ROWS / 128), 256, 0, stream>>>(
        x, Ph, Pl, proj, Ahq, Alq);
    row_norm_kernel<<<M_ROWS / 4, 256, 0, stream>>>(proj, invr, nullptr, nullptr);
    mfma_argmax_kernel<<<(M_ROWS / 128) * (K_CB / 128), 256, 0, stream>>>(
        Ahq, Alq, Bhq, Blq, invr, invc, cnsq, sB, candb, cands2, candi);
    combine2_kernel<<<M_ROWS / 256, 256, 0, stream>>>(
        candb, cands2, candi, out, bqv, fixlist, fixcount);
    fix_exact_kernel<<<256, 256, 0, stream>>>(
        proj, cb, invr, invc, cnsq, candb, bqv, fixlist, fixcount, out);
  } else {
    float* ws    = (float*)d_ws;
    float* proj1 = ws;
    float* invr1 = proj1 + (size_t)M_ROWS * E_DIM;
    float* invc1 = invr1 + M_ROWS;
    float* cnsq1 = invc1 + K_CB;
    float* cands = cnsq1 + K_CB;
    int*   candi1 = (int*)(cands + (size_t)M_ROWS * 2);

    row_norm_kernel<<<K_CB / 4, 256, 0, stream>>>(cb, invc1, cnsq1, nullptr);
    gemm1_kernel<<<dim3(E_DIM / 128, M_ROWS / 128), 256, 0, stream>>>(x, rp, proj1);
    row_norm_kernel<<<M_ROWS / 4, 256, 0, stream>>>(proj1, invr1, nullptr, nullptr);
    argmax_kernel<<<dim3(M_ROWS / 64, 2), 256, 0, stream>>>(proj1, cb, invr1,
                                                            invc1, cnsq1, cands, candi1);
    combine_kernel<<<M_ROWS / 256, 256, 0, stream>>>(cands, candi1, out);
  }
}